// Round 5
// baseline (873.116 us; speedup 1.0000x reference)
//
#include <hip/hip_runtime.h>
#include <math.h>

#define KGRID 1024
#define NIMG  512
#define JW    6
#define BETAF 14.04f   // 2.34 * J
#define NB    8        // batch count (fixed by problem)
#define TILE  32       // tile side in grid cells
#define NBIN  1024     // (1024/TILE)^2
#define CAP   512      // max point-entries per bin (mean ~264)
#define NW    16       // waves per grid_tile block (1024 threads)

// ---------- Kaiser-Bessel I0 (Abramowitz & Stegun 9.8.1 / 9.8.2, ~2e-7 rel) ----------
__device__ __forceinline__ float i0f_dev(float x) {
    float ax = fabsf(x);
    if (ax < 3.75f) {
        float z = ax * (1.0f / 3.75f);
        z = z * z;
        return 1.0f + z * (3.5156229f + z * (3.0899424f + z * (1.2067492f +
               z * (0.2659732f + z * (0.0360768f + z * 0.0045813f)))));
    } else {
        float z = 3.75f / ax;
        float p = 0.39894228f + z * (0.01328592f + z * (0.00225319f + z * (-0.00157565f +
                  z * (0.00916281f + z * (-0.02057706f + z * (0.02635537f +
                  z * (-0.01647633f + z * 0.00392377f)))))));
        return expf(ax) * rsqrtf(ax) * p;
    }
}

// ---------- Phase 0: pack y into per-point lines + uvw float4 ----------
// yP[m*8+b] = (yr[b][m], yi[b][m])  -> one 64B line per point for all 8 batches.
// uvw[m] = (u, v, wts*inv_i0^2, 0)
__global__ __launch_bounds__(256) void pack_y(
    const float* __restrict__ yr, const float* __restrict__ yi,
    const float* __restrict__ uv, const float* __restrict__ wts,
    float2* __restrict__ yP, float4* __restrict__ uvw, int M)
{
    int m = blockIdx.x * 256 + threadIdx.x;
    if (m >= M) return;
    float inv = 1.0f / i0f_dev(BETAF);
    float s2 = inv * inv;
    #pragma unroll
    for (int b = 0; b < NB; b++)
        yP[(size_t)m * NB + b] = make_float2(yr[(size_t)b * M + m], yi[(size_t)b * M + m]);
    uvw[m] = make_float4(uv[2 * m], uv[2 * m + 1], wts[m] * s2, 0.0f);
}

// ---------- Phase A: bin measurements into 32x32-cell tiles (<=4 bins each) ----------
__global__ __launch_bounds__(256) void bin_kernel(const float* __restrict__ uv, int M,
                                                  int* __restrict__ cnt, int* __restrict__ list)
{
    int m = blockIdx.x * 256 + threadIdx.x;
    if (m >= M) return;
    const float c2g = (float)KGRID / 6.283185307179586f;
    float kx = uv[2 * m]     * c2g;
    float ky = uv[2 * m + 1] * c2g;
    int x0m = (((int)floorf(kx - 3.0f) + 1) + 1024) & 1023;
    int y0m = (((int)floorf(ky - 3.0f) + 1) + 1024) & 1023;
    int txA = x0m >> 5, txB = ((x0m + 5) & 1023) >> 5;
    int tyA = y0m >> 5, tyB = ((y0m + 5) & 1023) >> 5;

    #define PUSH(tx, ty) { int bin = ((tx) << 5) | (ty);                 \
                           int slot = atomicAdd(&cnt[bin], 1);           \
                           if (slot < CAP) list[bin * CAP + slot] = m; }
    PUSH(txA, tyA);
    if (tyB != tyA)  PUSH(txA, tyB);
    if (txB != txA) { PUSH(txB, tyA); if (tyB != tyA) PUSH(txB, tyB); }
    #undef PUSH
}

// ---------- Phase B: per-tile gridding in LDS, single coalesced flush ----------
// 1024 threads = 16 waves; wave w handles points w, w+16, ... of its bin.
// Lane l: j2 = l>>3 (y-tap), b = l&7. Lane-parallel I0: lanes 0..5 eval wx[lane],
// lanes 6..11 eval wy[lane-6]; broadcast via __shfl. One I0 eval/point (was 7).
__global__ __launch_bounds__(1024, 8) void grid_tile(
    const float4* __restrict__ uvw, const float2* __restrict__ yP,
    const int* __restrict__ cnt, const int* __restrict__ list,
    float* __restrict__ gI)
{
    __shared__ float S[16384];   // [lx][ly][b][c]

    int tile = blockIdx.x;
    int tx0 = (tile >> 5) << 5;
    int ty0 = (tile & 31) << 5;
    int tid = threadIdx.x;

    float4* s4 = (float4*)S;
    for (int q = tid; q < 4096; q += 1024) s4[q] = make_float4(0.f, 0.f, 0.f, 0.f);
    __syncthreads();

    int n = cnt[tile]; if (n > CAP) n = CAP;
    const int* lst = list + tile * CAP;

    int wid  = tid >> 6;
    int lane = tid & 63;
    int j2 = lane >> 3;
    int b  = lane & 7;
    bool yact = (j2 < JW);
    const float c2g = (float)KGRID / 6.283185307179586f;

    // depth-2 software pipeline
    int iA = wid;
    int mA = (iA < n) ? lst[iA] : 0;
    float4 fA = make_float4(0.f,0.f,0.f,0.f);
    float2 yA = make_float2(0.f,0.f);
    if (iA < n) { fA = uvw[mA]; yA = yP[(size_t)mA * NB + b]; }
    int iB = iA + NW;
    int mB = (iB < n) ? lst[iB] : 0;

    while (iA < n) {
        float4 fB = make_float4(0.f,0.f,0.f,0.f);
        float2 yB = make_float2(0.f,0.f);
        if (iB < n) { fB = uvw[mB]; yB = yP[(size_t)mB * NB + b]; }
        int iC = iB + NW;
        int mC = (iC < n) ? lst[iC] : 0;

        // ---- compute point A ----
        float kx = fA.x * c2g, ky = fA.y * c2g;
        float sc = fA.z;
        float kmx = floorf(kx - 3.0f), kmy = floorf(ky - 3.0f);

        float kk  = (lane < 6) ? kx  : ky;
        float kmf = (lane < 6) ? kmx : kmy;
        int   jj  = (lane < 6) ? lane : lane - 6;
        float dd  = kk - kmf - 1.0f - (float)jj;
        float rr  = dd * (1.0f / 3.0f);
        float aa  = fmaxf(1.0f - rr * rr, 0.0f);
        float wj  = i0f_dev(BETAF * sqrtf(aa));

        float wyl = __shfl(wj, 6 + j2);

        int x0m = (((int)kmx + 1) + 1024) & 1023;
        int y0m = (((int)kmy + 1) + 1024) & 1023;
        int ly  = ((y0m + j2) & 1023) - ty0;
        bool yok = yact && ((unsigned)ly < 32u);
        float yrw = yA.x * sc * wyl;
        float yiw = yA.y * sc * wyl;

        #pragma unroll
        for (int j1 = 0; j1 < JW; j1++) {
            float wx = __shfl(wj, j1);
            int lx = ((x0m + j1) & 1023) - tx0;
            if (yok && ((unsigned)lx < 32u)) {
                int a = (((lx << 5) + ly) << 4) + (b << 1);
                unsafeAtomicAdd(&S[a],     yrw * wx);
                unsafeAtomicAdd(&S[a + 1], yiw * wx);
            }
        }

        iA = iB; fA = fB; yA = yB;
        iB = iC; mB = mC;
    }
    __syncthreads();

    // flush: local float idx f = lx*512 + rem; global = (tx0+lx)*16384 + ty0*16 + rem
    float4* g4 = (float4*)gI;
    for (int q = tid; q < 4096; q += 1024) {
        int f   = q << 2;
        int lx  = f >> 9;
        int rem = f & 511;
        g4[(((size_t)(tx0 + lx)) << 12) + ((size_t)ty0 << 2) + (rem >> 2)] = s4[q];
    }
}

// ---------- Stockham radix-2 1024-pt inverse (e^{+i}) FFT in LDS ----------
__device__ __forceinline__ void fft1024_inv(float2* X, float2* Y, const float2* W, int tid)
{
    float2* src = X;
    float2* dst = Y;
    #pragma unroll
    for (int stage = 0; stage < 10; stage++) {
        const int s = 1 << stage;
        __syncthreads();
        #pragma unroll
        for (int h = 0; h < 2; h++) {
            int t  = tid + (h << 8);
            int sp = t & ~(s - 1);
            float2 c0 = src[t];
            float2 c1 = src[t + 512];
            float2 sum = make_float2(c0.x + c1.x, c0.y + c1.y);
            float2 dif = make_float2(c0.x - c1.x, c0.y - c1.y);
            float2 w = W[sp];
            dst[t + sp]     = sum;
            dst[t + sp + s] = make_float2(w.x * dif.x - w.y * dif.y,
                                          w.x * dif.y + w.y * dif.x);
        }
        float2* tmp = src; src = dst; dst = tmp;
    }
    __syncthreads();
}

// ---------- Pass 1: rows (k2 -> x2); keep 512 shifted cols; store transposed ----------
__global__ __launch_bounds__(256) void fft_pass1(const float2* __restrict__ gI,
                                                 float2* __restrict__ T)
{
    __shared__ float2 A[1024];
    __shared__ float2 Bb[1024];
    __shared__ float2 W[512];

    int blk = blockIdx.x;
    int k1  = ((blk >> 6) << 3) | (blk & 7);
    int b   = (blk >> 3) & 7;
    int tid = threadIdx.x;

    const float2* row = gI + ((size_t)k1 << 13) + b;
    #pragma unroll
    for (int h = 0; h < 4; h++) {
        int i = tid + (h << 8);
        A[i] = row[(size_t)i << 3];
    }
    #pragma unroll
    for (int h = 0; h < 2; h++) {
        int j = tid + (h << 8);
        float sn, cn;
        __sincosf(6.283185307179586f * (float)j * (1.0f / 1024.0f), &sn, &cn);
        W[j] = make_float2(cn, sn);
    }

    fft1024_inv(A, Bb, W, tid);

    float2* Tb = T + (((size_t)b * 512) << 10) + k1;
    #pragma unroll
    for (int h = 0; h < 2; h++) {
        int xo2 = tid + (h << 8);
        int x2  = (xo2 + 768) & 1023;
        Tb[(size_t)xo2 << 10] = A[x2];
    }
}

// ---------- de-apodization (matches _deapod) ----------
__device__ __forceinline__ float apodf(int n) {
    float x  = ((float)n - 256.0f) * (1.0f / 1024.0f);
    float px = 3.14159265358979f * 6.0f * x;
    float t  = BETAF * BETAF - px * px;
    float st = sqrtf(fabsf(t));
    float num = (t > 0.0f) ? sinhf(st) : __sinf(st);
    return num / fmaxf(st, 1e-6f);
}

// ---------- Pass 2: columns (k1 -> x1), fuse shift/crop/real/de-apod ----------
__global__ __launch_bounds__(256) void fft_pass2(const float2* __restrict__ T,
                                                 float* __restrict__ out)
{
    __shared__ float2 A[1024];
    __shared__ float2 Bb[1024];
    __shared__ float2 W[512];

    int blk = blockIdx.x;
    int b   = blk >> 9;
    int xo2 = blk & 511;
    int tid = threadIdx.x;

    const float2* row = T + (((size_t)b * 512 + xo2) << 10);
    #pragma unroll
    for (int h = 0; h < 4; h++) { int i = tid + (h << 8); A[i] = row[i]; }
    #pragma unroll
    for (int h = 0; h < 2; h++) {
        int j = tid + (h << 8);
        float sn, cn;
        __sincosf(6.283185307179586f * (float)j * (1.0f / 1024.0f), &sn, &cn);
        W[j] = make_float2(cn, sn);
    }

    fft1024_inv(A, Bb, W, tid);

    float a2 = apodf(xo2);
    #pragma unroll
    for (int h = 0; h < 2; h++) {
        int xo1 = tid + (h << 8);
        int x1  = (xo1 + 768) & 1023;
        float a1 = apodf(xo1);
        out[((size_t)b * 512 + xo1) * 512 + xo2] = A[x1].x / (a1 * a2);
    }
}

// ---------- host launch ----------
extern "C" void kernel_launch(void* const* d_in, const int* in_sizes, int n_in,
                              void* d_out, int out_size, void* d_ws, size_t ws_size,
                              hipStream_t stream)
{
    const float* yr  = (const float*)d_in[0];
    const float* yi  = (const float*)d_in[1];
    const float* uv  = (const float*)d_in[2];
    const float* wts = (const float*)d_in[3];

    int M = in_sizes[3];

    const size_t gridBytes = (size_t)KGRID * KGRID * NB * sizeof(float2);  // 64 MB
    float*  gI = (float*)d_ws;
    char*   p2 = (char*)d_ws + gridBytes;
    float2* T  = (float2*)p2;                        // 32 MB, pass1/pass2 only
    // bin-phase scratch ALIASES T (temporally disjoint with pass1/pass2):
    int*    cnt  = (int*)p2;                         // 4 KB
    int*    list = (int*)(p2 + 4096);                // 2 MB
    float2* yP   = (float2*)(p2 + (4u << 20));       // 12.8 MB @ +4MB
    float4* uvw  = (float4*)(p2 + (20u << 20));      // 3.2 MB @ +20MB

    hipMemsetAsync(cnt, 0, NBIN * sizeof(int), stream);
    pack_y<<<dim3((M + 255) / 256), dim3(256), 0, stream>>>(yr, yi, uv, wts, yP, uvw, M);
    bin_kernel<<<dim3((M + 255) / 256), dim3(256), 0, stream>>>(uv, M, cnt, list);
    grid_tile<<<dim3(NBIN), dim3(1024), 0, stream>>>(uvw, yP, cnt, list, gI);
    fft_pass1<<<dim3(NB * 1024), dim3(256), 0, stream>>>((const float2*)gI, T);
    fft_pass2<<<dim3(NB * 512), dim3(256), 0, stream>>>(T, (float*)d_out);
}

// Round 6
// 371.244 us; speedup vs baseline: 2.3519x; 2.3519x over previous
//
#include <hip/hip_runtime.h>
#include <math.h>

#define KGRID 1024
#define NIMG  512
#define JW    6
#define BETAF 14.04f   // 2.34 * J
#define NB    8        // batch count (fixed by problem)
#define TILE  16       // tile side in grid cells (wave-exclusive)
#define NBIN  4096     // (1024/TILE)^2
#define CAP   192      // max point-entries per bin (mean ~84, uniform uv)

// ---------- Kaiser-Bessel I0 (Abramowitz & Stegun 9.8.1 / 9.8.2, ~2e-7 rel) ----------
__device__ __forceinline__ float i0f_dev(float x) {
    float ax = fabsf(x);
    if (ax < 3.75f) {
        float z = ax * (1.0f / 3.75f);
        z = z * z;
        return 1.0f + z * (3.5156229f + z * (3.0899424f + z * (1.2067492f +
               z * (0.2659732f + z * (0.0360768f + z * 0.0045813f)))));
    } else {
        float z = 3.75f / ax;
        float p = 0.39894228f + z * (0.01328592f + z * (0.00225319f + z * (-0.00157565f +
                  z * (0.00916281f + z * (-0.02057706f + z * (0.02635537f +
                  z * (-0.01647633f + z * 0.00392377f)))))));
        return expf(ax) * rsqrtf(ax) * p;
    }
}

// ---------- Phase 0: pack y into per-point lines + uvw float4 ----------
__global__ __launch_bounds__(256) void pack_y(
    const float* __restrict__ yr, const float* __restrict__ yi,
    const float* __restrict__ uv, const float* __restrict__ wts,
    float2* __restrict__ yP, float4* __restrict__ uvw, int M)
{
    int m = blockIdx.x * 256 + threadIdx.x;
    if (m >= M) return;
    float inv = 1.0f / i0f_dev(BETAF);
    float s2 = inv * inv;
    #pragma unroll
    for (int b = 0; b < NB; b++)
        yP[(size_t)m * NB + b] = make_float2(yr[(size_t)b * M + m], yi[(size_t)b * M + m]);
    uvw[m] = make_float4(uv[2 * m], uv[2 * m + 1], wts[m] * s2, 0.0f);
}

// ---------- Phase A: bin measurements into 16x16-cell tiles (<=4 bins each) ----------
__global__ __launch_bounds__(256) void bin_kernel(const float* __restrict__ uv, int M,
                                                  int* __restrict__ cnt, int* __restrict__ list)
{
    int m = blockIdx.x * 256 + threadIdx.x;
    if (m >= M) return;
    const float c2g = (float)KGRID / 6.283185307179586f;
    float kx = uv[2 * m]     * c2g;
    float ky = uv[2 * m + 1] * c2g;
    int x0m = (((int)floorf(kx - 3.0f) + 1) + 1024) & 1023;
    int y0m = (((int)floorf(ky - 3.0f) + 1) + 1024) & 1023;
    int txA = x0m >> 4, txB = ((x0m + 5) & 1023) >> 4;
    int tyA = y0m >> 4, tyB = ((y0m + 5) & 1023) >> 4;

    #define PUSH(tx, ty) { int bin = ((tx) << 6) | (ty);                 \
                           int slot = atomicAdd(&cnt[bin], 1);           \
                           if (slot < CAP) list[bin * CAP + slot] = m; }
    PUSH(txA, tyA);
    if (tyB != tyA)  PUSH(txA, tyB);
    if (txB != txA) { PUSH(txB, tyA); if (tyB != tyA) PUSH(txB, tyB); }
    #undef PUSH
}

// ---------- Phase B: ONE WAVE per 16x16 tile, atomic-free LDS accumulation ----------
// Lane l: j2 = l>>3 (y-tap, active if <6), b = l&7. For a single point the 48
// active lanes hit 48 DISTINCT cells (distinct ly per j2, distinct slot per b),
// so plain ds_read_b64 / fma / ds_write_b64 is race-free; across points the
// same-wave DS FIFO guarantees RMW ordering. No atomics anywhere.
__global__ __launch_bounds__(64) void grid_tile(
    const float4* __restrict__ uvw, const float2* __restrict__ yP,
    const int* __restrict__ cnt, const int* __restrict__ list,
    float* __restrict__ gI)
{
    __shared__ float2 S2[TILE * TILE * NB];   // [lx][ly][b] = 16 KB

    int tile = blockIdx.x;
    int tx0 = (tile >> 6) << 4;
    int ty0 = (tile & 63) << 4;
    int lane = threadIdx.x;

    float4* s4 = (float4*)S2;
    #pragma unroll
    for (int q = 0; q < 16; q++) s4[lane + (q << 6)] = make_float4(0.f, 0.f, 0.f, 0.f);

    int n = cnt[tile]; if (n > CAP) n = CAP;
    const int* lst = list + tile * CAP;

    int j2 = lane >> 3;
    int b  = lane & 7;
    bool yact = (j2 < JW);
    const float c2g = (float)KGRID / 6.283185307179586f;

    // depth-2 software pipeline over the bin's points
    int iA = 0;
    int mA = (iA < n) ? lst[iA] : 0;
    float4 fA = make_float4(0.f,0.f,0.f,0.f);
    float2 yA = make_float2(0.f,0.f);
    if (iA < n) { fA = uvw[mA]; yA = yP[(size_t)mA * NB + b]; }
    int iB = 1;
    int mB = (iB < n) ? lst[iB] : 0;

    while (iA < n) {
        float4 fB = make_float4(0.f,0.f,0.f,0.f);
        float2 yB = make_float2(0.f,0.f);
        if (iB < n) { fB = uvw[mB]; yB = yP[(size_t)mB * NB + b]; }
        int iC = iB + 1;
        int mC = (iC < n) ? lst[iC] : 0;

        // ---- point A ----
        float kx = fA.x * c2g, ky = fA.y * c2g;
        float sc = fA.z;
        float kmx = floorf(kx - 3.0f), kmy = floorf(ky - 3.0f);

        // lane-parallel KB weights: lanes 0..5 -> wx[j], lanes 6..11 -> wy[j]
        float kk  = (lane < 6) ? kx  : ky;
        float kmf = (lane < 6) ? kmx : kmy;
        int   jj  = (lane < 6) ? lane : lane - 6;
        float dd  = kk - kmf - 1.0f - (float)jj;
        float rr  = dd * (1.0f / 3.0f);
        float aa  = fmaxf(1.0f - rr * rr, 0.0f);
        float wj  = i0f_dev(BETAF * sqrtf(aa));

        float wyl = __shfl(wj, 6 + j2);

        int x0m = (((int)kmx + 1) + 1024) & 1023;
        int y0m = (((int)kmy + 1) + 1024) & 1023;
        int ly  = ((y0m + j2) & 1023) - ty0;
        bool yok = yact && ((unsigned)ly < (unsigned)TILE);
        float yrw = yA.x * sc * wyl;
        float yiw = yA.y * sc * wyl;

        #pragma unroll
        for (int j1 = 0; j1 < JW; j1++) {
            int lx = ((x0m + j1) & 1023) - tx0;   // wave-uniform
            if ((unsigned)lx < (unsigned)TILE) {
                float wx = __shfl(wj, j1);
                if (yok) {
                    int a = (((lx << 4) + ly) << 3) + b;
                    float2 vv = S2[a];
                    vv.x += yrw * wx;
                    vv.y += yiw * wx;
                    S2[a] = vv;
                }
            }
        }

        iA = iB; fA = fB; yA = yB;
        iB = iC; mB = mC;
    }

    // flush: row (tx0+r) -> 64 float4 = 1 KB contiguous; lane = float4 index
    float4* g4 = (float4*)gI;
    #pragma unroll
    for (int r = 0; r < TILE; r++) {
        g4[((size_t)(tx0 + r) << 12) + ((size_t)ty0 << 2) + lane] = s4[(r << 6) + lane];
    }
}

// ---------- Stockham radix-2 1024-pt inverse (e^{+i}) FFT in LDS ----------
__device__ __forceinline__ void fft1024_inv(float2* X, float2* Y, const float2* W, int tid)
{
    float2* src = X;
    float2* dst = Y;
    #pragma unroll
    for (int stage = 0; stage < 10; stage++) {
        const int s = 1 << stage;
        __syncthreads();
        #pragma unroll
        for (int h = 0; h < 2; h++) {
            int t  = tid + (h << 8);
            int sp = t & ~(s - 1);
            float2 c0 = src[t];
            float2 c1 = src[t + 512];
            float2 sum = make_float2(c0.x + c1.x, c0.y + c1.y);
            float2 dif = make_float2(c0.x - c1.x, c0.y - c1.y);
            float2 w = W[sp];
            dst[t + sp]     = sum;
            dst[t + sp + s] = make_float2(w.x * dif.x - w.y * dif.y,
                                          w.x * dif.y + w.y * dif.x);
        }
        float2* tmp = src; src = dst; dst = tmp;
    }
    __syncthreads();
}

// ---------- Pass 1: rows (k2 -> x2); keep 512 shifted cols; store transposed ----------
__global__ __launch_bounds__(256) void fft_pass1(const float2* __restrict__ gI,
                                                 float2* __restrict__ T)
{
    __shared__ float2 A[1024];
    __shared__ float2 Bb[1024];
    __shared__ float2 W[512];

    int blk = blockIdx.x;
    int k1  = ((blk >> 6) << 3) | (blk & 7);
    int b   = (blk >> 3) & 7;
    int tid = threadIdx.x;

    const float2* row = gI + ((size_t)k1 << 13) + b;
    #pragma unroll
    for (int h = 0; h < 4; h++) {
        int i = tid + (h << 8);
        A[i] = row[(size_t)i << 3];
    }
    #pragma unroll
    for (int h = 0; h < 2; h++) {
        int j = tid + (h << 8);
        float sn, cn;
        __sincosf(6.283185307179586f * (float)j * (1.0f / 1024.0f), &sn, &cn);
        W[j] = make_float2(cn, sn);
    }

    fft1024_inv(A, Bb, W, tid);

    float2* Tb = T + (((size_t)b * 512) << 10) + k1;
    #pragma unroll
    for (int h = 0; h < 2; h++) {
        int xo2 = tid + (h << 8);
        int x2  = (xo2 + 768) & 1023;
        Tb[(size_t)xo2 << 10] = A[x2];
    }
}

// ---------- de-apodization (matches _deapod) ----------
__device__ __forceinline__ float apodf(int n) {
    float x  = ((float)n - 256.0f) * (1.0f / 1024.0f);
    float px = 3.14159265358979f * 6.0f * x;
    float t  = BETAF * BETAF - px * px;
    float st = sqrtf(fabsf(t));
    float num = (t > 0.0f) ? sinhf(st) : __sinf(st);
    return num / fmaxf(st, 1e-6f);
}

// ---------- Pass 2: columns (k1 -> x1), fuse shift/crop/real/de-apod ----------
__global__ __launch_bounds__(256) void fft_pass2(const float2* __restrict__ T,
                                                 float* __restrict__ out)
{
    __shared__ float2 A[1024];
    __shared__ float2 Bb[1024];
    __shared__ float2 W[512];

    int blk = blockIdx.x;
    int b   = blk >> 9;
    int xo2 = blk & 511;
    int tid = threadIdx.x;

    const float2* row = T + (((size_t)b * 512 + xo2) << 10);
    #pragma unroll
    for (int h = 0; h < 4; h++) { int i = tid + (h << 8); A[i] = row[i]; }
    #pragma unroll
    for (int h = 0; h < 2; h++) {
        int j = tid + (h << 8);
        float sn, cn;
        __sincosf(6.283185307179586f * (float)j * (1.0f / 1024.0f), &sn, &cn);
        W[j] = make_float2(cn, sn);
    }

    fft1024_inv(A, Bb, W, tid);

    float a2 = apodf(xo2);
    #pragma unroll
    for (int h = 0; h < 2; h++) {
        int xo1 = tid + (h << 8);
        int x1  = (xo1 + 768) & 1023;
        float a1 = apodf(xo1);
        out[((size_t)b * 512 + xo1) * 512 + xo2] = A[x1].x / (a1 * a2);
    }
}

// ---------- host launch ----------
extern "C" void kernel_launch(void* const* d_in, const int* in_sizes, int n_in,
                              void* d_out, int out_size, void* d_ws, size_t ws_size,
                              hipStream_t stream)
{
    const float* yr  = (const float*)d_in[0];
    const float* yi  = (const float*)d_in[1];
    const float* uv  = (const float*)d_in[2];
    const float* wts = (const float*)d_in[3];

    int M = in_sizes[3];

    const size_t gridBytes = (size_t)KGRID * KGRID * NB * sizeof(float2);  // 64 MB
    float*  gI = (float*)d_ws;
    char*   p2 = (char*)d_ws + gridBytes;
    float2* T  = (float2*)p2;                        // 32 MB, pass1/pass2 only
    // bin-phase scratch ALIASES T (temporally disjoint with pass1/pass2):
    int*    cnt  = (int*)p2;                         // 16 KB
    int*    list = (int*)(p2 + (64u << 10));         // 3 MB   (4096*192*4)
    float2* yP   = (float2*)(p2 + (4u << 20));       // 12.8 MB @ +4MB
    float4* uvw  = (float4*)(p2 + (20u << 20));      // 3.2 MB @ +20MB

    hipMemsetAsync(cnt, 0, NBIN * sizeof(int), stream);
    pack_y<<<dim3((M + 255) / 256), dim3(256), 0, stream>>>(yr, yi, uv, wts, yP, uvw, M);
    bin_kernel<<<dim3((M + 255) / 256), dim3(256), 0, stream>>>(uv, M, cnt, list);
    grid_tile<<<dim3(NBIN), dim3(64), 0, stream>>>(uvw, yP, cnt, list, gI);
    fft_pass1<<<dim3(NB * 1024), dim3(256), 0, stream>>>((const float2*)gI, T);
    fft_pass2<<<dim3(NB * 512), dim3(256), 0, stream>>>(T, (float*)d_out);
}

// Round 7
// 353.202 us; speedup vs baseline: 2.4720x; 1.0511x over previous
//
#include <hip/hip_runtime.h>
#include <math.h>

#define KGRID 1024
#define NIMG  512
#define JW    6
#define BETAF 14.04f   // 2.34 * J
#define NB    8        // batch count (fixed by problem)
#define TILE  16       // tile side in grid cells (wave-exclusive)
#define NBIN  4096     // (1024/TILE)^2
#define CAP   192      // max point-entries per bin (mean ~84, uniform uv)

// ---------- Kaiser-Bessel I0 (Abramowitz & Stegun 9.8.1 / 9.8.2, ~2e-7 rel) ----------
__device__ __forceinline__ float i0f_dev(float x) {
    float ax = fabsf(x);
    if (ax < 3.75f) {
        float z = ax * (1.0f / 3.75f);
        z = z * z;
        return 1.0f + z * (3.5156229f + z * (3.0899424f + z * (1.2067492f +
               z * (0.2659732f + z * (0.0360768f + z * 0.0045813f)))));
    } else {
        float z = 3.75f / ax;
        float p = 0.39894228f + z * (0.01328592f + z * (0.00225319f + z * (-0.00157565f +
                  z * (0.00916281f + z * (-0.02057706f + z * (0.02635537f +
                  z * (-0.01647633f + z * 0.00392377f)))))));
        return expf(ax) * rsqrtf(ax) * p;
    }
}

// ---------- Phase 0 (fused): pack y lines + uvw float4 + bin into tiles ----------
__global__ __launch_bounds__(256) void prep_kernel(
    const float* __restrict__ yr, const float* __restrict__ yi,
    const float* __restrict__ uv, const float* __restrict__ wts,
    float2* __restrict__ yP, float4* __restrict__ uvw,
    int* __restrict__ cnt, int* __restrict__ list, int M)
{
    int m = blockIdx.x * 256 + threadIdx.x;
    if (m >= M) return;
    float inv = 1.0f / i0f_dev(BETAF);
    float s2 = inv * inv;
    #pragma unroll
    for (int b = 0; b < NB; b++)
        yP[(size_t)m * NB + b] = make_float2(yr[(size_t)b * M + m], yi[(size_t)b * M + m]);
    float u = uv[2 * m], v = uv[2 * m + 1];
    uvw[m] = make_float4(u, v, wts[m] * s2, 0.0f);

    const float c2g = (float)KGRID / 6.283185307179586f;
    float kx = u * c2g, ky = v * c2g;
    int x0m = (((int)floorf(kx - 3.0f) + 1) + 1024) & 1023;
    int y0m = (((int)floorf(ky - 3.0f) + 1) + 1024) & 1023;
    int txA = x0m >> 4, txB = ((x0m + 5) & 1023) >> 4;
    int tyA = y0m >> 4, tyB = ((y0m + 5) & 1023) >> 4;

    #define PUSH(tx, ty) { int bin = ((tx) << 6) | (ty);                 \
                           int slot = atomicAdd(&cnt[bin], 1);           \
                           if (slot < CAP) list[bin * CAP + slot] = m; }
    PUSH(txA, tyA);
    if (tyB != tyA)  PUSH(txA, tyB);
    if (txB != txA) { PUSH(txB, tyA); if (tyB != tyA) PUSH(txB, tyB); }
    #undef PUSH
}

// ---------- Phase B: ONE WAVE per 16x16 tile, atomic-free, batched-DS RMW ----------
// Lane l: j2 = l>>3 (y-tap, active if <6), b = l&7. Within one point the 6 j1
// targets of a lane are DISTINCT cells (lx varies, ly/b fixed), so all 6
// ds_read_b64 issue before the fma/ds_write batch -> ONE DS round-trip per
// point (was ~4.6 serialized). Out-of-tile lanes are predicated by address:
// they RMW a per-lane dummy slot (2048+lane) that is never flushed.
// Cross-point RMW ordering is guaranteed by the wave's in-order DS FIFO.
__global__ __launch_bounds__(64) void grid_tile(
    const float4* __restrict__ uvw, const float2* __restrict__ yP,
    const int* __restrict__ cnt, const int* __restrict__ list,
    float* __restrict__ gI)
{
    __shared__ float2 S2[TILE * TILE * NB + 64];   // 2048 cells + 64 dummy = 16.5 KB

    int tile = blockIdx.x;
    int tx0 = (tile >> 6) << 4;
    int ty0 = (tile & 63) << 4;
    int lane = threadIdx.x;

    float4* s4 = (float4*)S2;
    for (int q = lane; q < 1056; q += 64) s4[q] = make_float4(0.f, 0.f, 0.f, 0.f);

    int n = cnt[tile]; if (n > CAP) n = CAP;
    const int* lst = list + tile * CAP;

    int j2 = lane >> 3;
    int b  = lane & 7;
    bool yact = (j2 < JW);
    const float c2g = (float)KGRID / 6.283185307179586f;

    // depth-2 software pipeline over the bin's points
    int iA = 0;
    int mA = (iA < n) ? lst[iA] : 0;
    float4 fA = make_float4(0.f,0.f,0.f,0.f);
    float2 yA = make_float2(0.f,0.f);
    if (iA < n) { fA = uvw[mA]; yA = yP[(size_t)mA * NB + b]; }
    int iB = 1;
    int mB = (iB < n) ? lst[iB] : 0;

    while (iA < n) {
        float4 fB = make_float4(0.f,0.f,0.f,0.f);
        float2 yB = make_float2(0.f,0.f);
        if (iB < n) { fB = uvw[mB]; yB = yP[(size_t)mB * NB + b]; }
        int iC = iB + 1;
        int mC = (iC < n) ? lst[iC] : 0;

        // ---- point A ----
        float kx = fA.x * c2g, ky = fA.y * c2g;
        float sc = fA.z;
        float kmx = floorf(kx - 3.0f), kmy = floorf(ky - 3.0f);

        // lane-parallel KB weights: lanes 0..5 -> wx[j], lanes 6..11 -> wy[j]
        float kk  = (lane < 6) ? kx  : ky;
        float kmf = (lane < 6) ? kmx : kmy;
        int   jj  = (lane < 6) ? lane : lane - 6;
        float dd  = kk - kmf - 1.0f - (float)jj;
        float rr  = dd * (1.0f / 3.0f);
        float aa  = fmaxf(1.0f - rr * rr, 0.0f);
        float wj  = i0f_dev(BETAF * sqrtf(aa));

        float wyl = __shfl(wj, 6 + j2);

        int x0m = (((int)kmx + 1) + 1024) & 1023;
        int y0m = (((int)kmy + 1) + 1024) & 1023;
        int lx0u = (x0m - tx0) & 1023;                  // wave-uniform
        int lyu  = (((y0m + j2) & 1023) - ty0) & 1023;  // per-lane
        bool yok = yact && (lyu < TILE);
        int lybase = ((lyu & 15) << 3) + b;
        float yrw = yA.x * sc * wyl;
        float yiw = yA.y * sc * wyl;

        int addr[JW];
        float2 vv[JW];
        #pragma unroll
        for (int j1 = 0; j1 < JW; j1++) {
            int lxj = lx0u + j1;
            bool xin = (lxj < TILE) | (lxj >= 1024);    // in-tile (handles wrap)
            int a = ((lxj & 15) << 7) + lybase;
            addr[j1] = (xin & yok) ? a : (2048 + lane);
        }
        #pragma unroll
        for (int j1 = 0; j1 < JW; j1++) vv[j1] = S2[addr[j1]];   // batched reads
        #pragma unroll
        for (int j1 = 0; j1 < JW; j1++) {
            float wx = __shfl(wj, j1);
            vv[j1].x = fmaf(yrw, wx, vv[j1].x);
            vv[j1].y = fmaf(yiw, wx, vv[j1].y);
            S2[addr[j1]] = vv[j1];
        }

        iA = iB; fA = fB; yA = yB;
        iB = iC; mB = mC;
    }

    // flush: row (tx0+r) -> 64 float4 = 1 KB contiguous; lane = float4 index
    float4* g4 = (float4*)gI;
    #pragma unroll
    for (int r = 0; r < TILE; r++) {
        g4[((size_t)(tx0 + r) << 12) + ((size_t)ty0 << 2) + lane] = s4[(r << 6) + lane];
    }
}

// ---------- Stockham radix-2 1024-pt inverse (e^{+i}) FFT in LDS ----------
__device__ __forceinline__ void fft1024_inv(float2* X, float2* Y, const float2* W, int tid)
{
    float2* src = X;
    float2* dst = Y;
    #pragma unroll
    for (int stage = 0; stage < 10; stage++) {
        const int s = 1 << stage;
        __syncthreads();
        #pragma unroll
        for (int h = 0; h < 2; h++) {
            int t  = tid + (h << 8);
            int sp = t & ~(s - 1);
            float2 c0 = src[t];
            float2 c1 = src[t + 512];
            float2 sum = make_float2(c0.x + c1.x, c0.y + c1.y);
            float2 dif = make_float2(c0.x - c1.x, c0.y - c1.y);
            float2 w = W[sp];
            dst[t + sp]     = sum;
            dst[t + sp + s] = make_float2(w.x * dif.x - w.y * dif.y,
                                          w.x * dif.y + w.y * dif.x);
        }
        float2* tmp = src; src = dst; dst = tmp;
    }
    __syncthreads();
}

// ---------- Pass 1: rows (k2 -> x2); keep 512 shifted cols; store transposed ----------
__global__ __launch_bounds__(256) void fft_pass1(const float2* __restrict__ gI,
                                                 float2* __restrict__ T)
{
    __shared__ float2 A[1024];
    __shared__ float2 Bb[1024];
    __shared__ float2 W[512];

    int blk = blockIdx.x;
    int k1  = ((blk >> 6) << 3) | (blk & 7);
    int b   = (blk >> 3) & 7;
    int tid = threadIdx.x;

    const float2* row = gI + ((size_t)k1 << 13) + b;
    #pragma unroll
    for (int h = 0; h < 4; h++) {
        int i = tid + (h << 8);
        A[i] = row[(size_t)i << 3];
    }
    #pragma unroll
    for (int h = 0; h < 2; h++) {
        int j = tid + (h << 8);
        float sn, cn;
        __sincosf(6.283185307179586f * (float)j * (1.0f / 1024.0f), &sn, &cn);
        W[j] = make_float2(cn, sn);
    }

    fft1024_inv(A, Bb, W, tid);

    float2* Tb = T + (((size_t)b * 512) << 10) + k1;
    #pragma unroll
    for (int h = 0; h < 2; h++) {
        int xo2 = tid + (h << 8);
        int x2  = (xo2 + 768) & 1023;
        Tb[(size_t)xo2 << 10] = A[x2];
    }
}

// ---------- de-apodization (matches _deapod) ----------
__device__ __forceinline__ float apodf(int n) {
    float x  = ((float)n - 256.0f) * (1.0f / 1024.0f);
    float px = 3.14159265358979f * 6.0f * x;
    float t  = BETAF * BETAF - px * px;
    float st = sqrtf(fabsf(t));
    float num = (t > 0.0f) ? sinhf(st) : __sinf(st);
    return num / fmaxf(st, 1e-6f);
}

// ---------- Pass 2: columns (k1 -> x1), fuse shift/crop/real/de-apod ----------
__global__ __launch_bounds__(256) void fft_pass2(const float2* __restrict__ T,
                                                 float* __restrict__ out)
{
    __shared__ float2 A[1024];
    __shared__ float2 Bb[1024];
    __shared__ float2 W[512];

    int blk = blockIdx.x;
    int b   = blk >> 9;
    int xo2 = blk & 511;
    int tid = threadIdx.x;

    const float2* row = T + (((size_t)b * 512 + xo2) << 10);
    #pragma unroll
    for (int h = 0; h < 4; h++) { int i = tid + (h << 8); A[i] = row[i]; }
    #pragma unroll
    for (int h = 0; h < 2; h++) {
        int j = tid + (h << 8);
        float sn, cn;
        __sincosf(6.283185307179586f * (float)j * (1.0f / 1024.0f), &sn, &cn);
        W[j] = make_float2(cn, sn);
    }

    fft1024_inv(A, Bb, W, tid);

    float a2 = apodf(xo2);
    #pragma unroll
    for (int h = 0; h < 2; h++) {
        int xo1 = tid + (h << 8);
        int x1  = (xo1 + 768) & 1023;
        float a1 = apodf(xo1);
        out[((size_t)b * 512 + xo1) * 512 + xo2] = A[x1].x / (a1 * a2);
    }
}

// ---------- host launch ----------
extern "C" void kernel_launch(void* const* d_in, const int* in_sizes, int n_in,
                              void* d_out, int out_size, void* d_ws, size_t ws_size,
                              hipStream_t stream)
{
    const float* yr  = (const float*)d_in[0];
    const float* yi  = (const float*)d_in[1];
    const float* uv  = (const float*)d_in[2];
    const float* wts = (const float*)d_in[3];

    int M = in_sizes[3];

    const size_t gridBytes = (size_t)KGRID * KGRID * NB * sizeof(float2);  // 64 MB
    float*  gI = (float*)d_ws;
    char*   p2 = (char*)d_ws + gridBytes;
    float2* T  = (float2*)p2;                        // 32 MB, pass1/pass2 only
    // bin-phase scratch ALIASES T (temporally disjoint with pass1/pass2):
    int*    cnt  = (int*)p2;                         // 16 KB
    int*    list = (int*)(p2 + (64u << 10));         // 3 MB   (4096*192*4)
    float2* yP   = (float2*)(p2 + (4u << 20));       // 12.8 MB @ +4MB
    float4* uvw  = (float4*)(p2 + (20u << 20));      // 3.2 MB @ +20MB

    hipMemsetAsync(cnt, 0, NBIN * sizeof(int), stream);
    prep_kernel<<<dim3((M + 255) / 256), dim3(256), 0, stream>>>(
        yr, yi, uv, wts, yP, uvw, cnt, list, M);
    grid_tile<<<dim3(NBIN), dim3(64), 0, stream>>>(uvw, yP, cnt, list, gI);
    fft_pass1<<<dim3(NB * 1024), dim3(256), 0, stream>>>((const float2*)gI, T);
    fft_pass2<<<dim3(NB * 512), dim3(256), 0, stream>>>(T, (float*)d_out);
}

// Round 8
// 350.356 us; speedup vs baseline: 2.4921x; 1.0081x over previous
//
#include <hip/hip_runtime.h>
#include <math.h>

#define KGRID 1024
#define NIMG  512
#define JW    6
#define BETAF 14.04f   // 2.34 * J
#define NB    8        // batch count (fixed by problem)
#define TILE  16       // tile side in grid cells (wave-exclusive, register-resident)
#define NBIN  4096     // (1024/TILE)^2
#define CAP   192      // max point-entries per bin (mean ~88 with 21-wide gather halo)

// ---------- Kaiser-Bessel I0 (Abramowitz & Stegun 9.8.1 / 9.8.2, ~2e-7 rel) ----------
__device__ __forceinline__ float i0f_dev(float x) {
    float ax = fabsf(x);
    if (ax < 3.75f) {
        float z = ax * (1.0f / 3.75f);
        z = z * z;
        return 1.0f + z * (3.5156229f + z * (3.0899424f + z * (1.2067492f +
               z * (0.2659732f + z * (0.0360768f + z * 0.0045813f)))));
    } else {
        float z = 3.75f / ax;
        float p = 0.39894228f + z * (0.01328592f + z * (0.00225319f + z * (-0.00157565f +
                  z * (0.00916281f + z * (-0.02057706f + z * (0.02635537f +
                  z * (-0.01647633f + z * 0.00392377f)))))));
        return expf(ax) * rsqrtf(ax) * p;
    }
}

// ---------- Phase 0 (fused): pack y lines + uvw float4 + gather-bin ----------
// Gather rule: tile tx receives points with x0m in [tx0-5, tx0+15]. Point pushes
// to its own tile (x0m>>4) always, and to the next tile iff (x0m&15) >= 11.
__global__ __launch_bounds__(256) void prep_kernel(
    const float* __restrict__ yr, const float* __restrict__ yi,
    const float* __restrict__ uv, const float* __restrict__ wts,
    float2* __restrict__ yP, float4* __restrict__ uvw,
    int* __restrict__ cnt, int* __restrict__ list, int M)
{
    int m = blockIdx.x * 256 + threadIdx.x;
    if (m >= M) return;
    float inv = 1.0f / i0f_dev(BETAF);
    float s2 = inv * inv;
    #pragma unroll
    for (int b = 0; b < NB; b++)
        yP[(size_t)m * NB + b] = make_float2(yr[(size_t)b * M + m], yi[(size_t)b * M + m]);
    float u = uv[2 * m], v = uv[2 * m + 1];
    uvw[m] = make_float4(u, v, wts[m] * s2, 0.0f);

    const float c2g = (float)KGRID / 6.283185307179586f;
    float kx = u * c2g, ky = v * c2g;
    int x0m = (((int)floorf(kx - 3.0f) + 1) + 1024) & 1023;
    int y0m = (((int)floorf(ky - 3.0f) + 1) + 1024) & 1023;
    int txA = x0m >> 4, txB = (txA + 1) & 63;
    int tyA = y0m >> 4, tyB = (tyA + 1) & 63;
    bool bx = (x0m & 15) >= 11;
    bool by = (y0m & 15) >= 11;

    #define PUSH(tx, ty) { int bin = ((tx) << 6) | (ty);                 \
                           int slot = atomicAdd(&cnt[bin], 1);           \
                           if (slot < CAP) list[bin * CAP + slot] = m; }
    PUSH(txA, tyA);
    if (by)  PUSH(txA, tyB);
    if (bx) { PUSH(txB, tyA); if (by) PUSH(txB, tyB); }
    #undef PUSH
}

// ---------- Phase B: gather-gridding, REGISTER accumulation, zero LDS ----------
// One wave per 16x16 tile. Lane l: ly = l>>2, bp = l&3 (owns batches 2bp, 2bp+1).
// acc[16] float4 = the lane's 16 lx cells x 2 batches (64 VGPR).
// Per point: lane-parallel KB weights in lanes 0-5 (wx) / 8-13 (wy), zeros in
// 6,7,14,15; per-lane wy via ds_bpermute; per-lx wx via scalar readlane with
// index clamped to a zero lane when lx is outside the footprint -> branch-free
// fmac with SGPR operand. No DS RMW, no atomics, no cross-point hazards.
__global__ __launch_bounds__(256, 4) void grid_tile(
    const float4* __restrict__ uvw, const float4* __restrict__ yF4,
    const int* __restrict__ cnt, const int* __restrict__ list,
    float2* __restrict__ gP)
{
    int lane = threadIdx.x & 63;
    int wid  = threadIdx.x >> 6;
    int tile = blockIdx.x * 4 + wid;
    int tx0 = (tile >> 6) << 4;
    int ty0 = (tile & 63) << 4;

    int ly = lane >> 2;
    int bp = lane & 3;

    float4 acc[16];
    #pragma unroll
    for (int i = 0; i < 16; i++) acc[i] = make_float4(0.f, 0.f, 0.f, 0.f);

    int n = cnt[tile]; if (n > CAP) n = CAP;
    const int* lst = list + tile * CAP;

    const float c2g = (float)KGRID / 6.283185307179586f;
    int jj = lane & 7;
    bool wlane = (jj < JW) && (lane < 16);
    bool isY = (lane & 8) != 0;

    // depth-2 software pipeline over the bin's points
    float4 fA = make_float4(0.f,0.f,0.f,0.f);
    float4 yA = make_float4(0.f,0.f,0.f,0.f);
    if (0 < n) { int m = lst[0]; fA = uvw[m]; yA = yF4[(size_t)m * 4 + bp]; }

    for (int i = 0; i < n; i++) {
        float4 fB = make_float4(0.f,0.f,0.f,0.f);
        float4 yB = make_float4(0.f,0.f,0.f,0.f);
        if (i + 1 < n) { int m1 = lst[i + 1]; fB = uvw[m1]; yB = yF4[(size_t)m1 * 4 + bp]; }

        float kx = fA.x * c2g, ky = fA.y * c2g;
        float sc = fA.z;
        float kmx = floorf(kx - 3.0f), kmy = floorf(ky - 3.0f);
        int x0m = (((int)kmx + 1) + 1024) & 1023;
        int y0m = (((int)kmy + 1) + 1024) & 1023;

        // lane-parallel KB weights
        float kk  = isY ? ky  : kx;
        float kmf = isY ? kmy : kmx;
        float dd  = kk - kmf - 1.0f - (float)jj;
        float rr  = dd * (1.0f / 3.0f);
        float aa  = fmaxf(1.0f - rr * rr, 0.0f);
        float wjv = i0f_dev(BETAF * sqrtf(aa));
        float wj  = wlane ? wjv : 0.0f;

        // per-lane wy (index-clamped into zero lanes 14/15)
        int j2 = (ty0 + ly - y0m) & 1023;
        int idxy = 8 + (j2 < 7 ? j2 : 7);
        float wyl = __int_as_float(__builtin_amdgcn_ds_bpermute(idxy << 2, __float_as_int(wj)));
        wyl *= sc;
        float4 ys = make_float4(yA.x * wyl, yA.y * wyl, yA.z * wyl, yA.w * wyl);

        int x0s = __builtin_amdgcn_readfirstlane(x0m);
        #pragma unroll
        for (int lx = 0; lx < 16; lx++) {
            int j1 = (tx0 + lx - x0s) & 1023;
            int idx = j1 < 7 ? j1 : 7;     // lanes 6/7 hold exact 0
            float wx = __int_as_float(__builtin_amdgcn_readlane(__float_as_int(wj), idx));
            acc[lx].x = fmaf(wx, ys.x, acc[lx].x);
            acc[lx].y = fmaf(wx, ys.y, acc[lx].y);
            acc[lx].z = fmaf(wx, ys.z, acc[lx].z);
            acc[lx].w = fmaf(wx, ys.w, acc[lx].w);
        }

        fA = fB; yA = yB;
    }

    // flush to PLANAR grid: plane b (1M float2) at b<<20; fully covers the tile
    int b0 = bp << 1;
    #pragma unroll
    for (int lx = 0; lx < 16; lx++) {
        size_t rowoff = ((size_t)(tx0 + lx) << 10) + (size_t)(ty0 + ly);
        gP[((size_t)b0 << 20) + rowoff]       = make_float2(acc[lx].x, acc[lx].y);
        gP[((size_t)(b0 + 1) << 20) + rowoff] = make_float2(acc[lx].z, acc[lx].w);
    }
}

// ---------- Stockham radix-2 1024-pt inverse (e^{+i}) FFT in LDS ----------
__device__ __forceinline__ void fft1024_inv(float2* X, float2* Y, const float2* W, int tid)
{
    float2* src = X;
    float2* dst = Y;
    #pragma unroll
    for (int stage = 0; stage < 10; stage++) {
        const int s = 1 << stage;
        __syncthreads();
        #pragma unroll
        for (int h = 0; h < 2; h++) {
            int t  = tid + (h << 8);
            int sp = t & ~(s - 1);
            float2 c0 = src[t];
            float2 c1 = src[t + 512];
            float2 sum = make_float2(c0.x + c1.x, c0.y + c1.y);
            float2 dif = make_float2(c0.x - c1.x, c0.y - c1.y);
            float2 w = W[sp];
            dst[t + sp]     = sum;
            dst[t + sp + s] = make_float2(w.x * dif.x - w.y * dif.y,
                                          w.x * dif.y + w.y * dif.x);
        }
        float2* tmp = src; src = dst; dst = tmp;
    }
    __syncthreads();
}

// ---------- Pass 1: rows (k2 -> x2) from PLANAR grid, 4 rows per block;
// keep 512 shifted cols; stage k1-block transpose in LDS -> 32B-aligned stores ----------
__global__ __launch_bounds__(256) void fft_pass1(const float2* __restrict__ gP,
                                                 float2* __restrict__ T)
{
    __shared__ float2 A[1024];
    __shared__ float2 Bb[1024];
    __shared__ float2 W[512];
    __shared__ float2 R[4][512];

    int blk = blockIdx.x;
    int b   = blk >> 8;          // 8 batches
    int k1g = blk & 255;         // 256 groups of 4 rows
    int tid = threadIdx.x;

    #pragma unroll
    for (int h = 0; h < 2; h++) {
        int j = tid + (h << 8);
        float sn, cn;
        __sincosf(6.283185307179586f * (float)j * (1.0f / 1024.0f), &sn, &cn);
        W[j] = make_float2(cn, sn);   // +i for inverse
    }

    for (int r = 0; r < 4; r++) {
        int k1 = (k1g << 2) + r;
        const float2* row = gP + ((size_t)b << 20) + ((size_t)k1 << 10);
        __syncthreads();   // prior R-phase reads of A done before overwrite
        #pragma unroll
        for (int h = 0; h < 4; h++) { int i = tid + (h << 8); A[i] = row[i]; }
        fft1024_inv(A, Bb, W, tid);
        #pragma unroll
        for (int h = 0; h < 2; h++) {
            int xo2 = tid + (h << 8);
            R[r][xo2] = A[(xo2 + 768) & 1023];   // fftshift+crop fold
        }
    }
    __syncthreads();

    #pragma unroll
    for (int h = 0; h < 2; h++) {
        int xo2 = tid + (h << 8);
        float2 f0 = R[0][xo2], f1 = R[1][xo2], f2 = R[2][xo2], f3 = R[3][xo2];
        float4* d4 = (float4*)(T + (((size_t)b * 512 + xo2) << 10) + (k1g << 2));
        d4[0] = make_float4(f0.x, f0.y, f1.x, f1.y);
        d4[1] = make_float4(f2.x, f2.y, f3.x, f3.y);
    }
}

// ---------- de-apodization (matches _deapod) ----------
__device__ __forceinline__ float apodf(int n) {
    float x  = ((float)n - 256.0f) * (1.0f / 1024.0f);
    float px = 3.14159265358979f * 6.0f * x;
    float t  = BETAF * BETAF - px * px;
    float st = sqrtf(fabsf(t));
    float num = (t > 0.0f) ? sinhf(st) : __sinf(st);
    return num / fmaxf(st, 1e-6f);
}

// ---------- Pass 2: columns (k1 -> x1), fuse shift/crop/real/de-apod ----------
__global__ __launch_bounds__(256) void fft_pass2(const float2* __restrict__ T,
                                                 float* __restrict__ out)
{
    __shared__ float2 A[1024];
    __shared__ float2 Bb[1024];
    __shared__ float2 W[512];

    int blk = blockIdx.x;
    int b   = blk >> 9;
    int xo2 = blk & 511;
    int tid = threadIdx.x;

    const float2* row = T + (((size_t)b * 512 + xo2) << 10);
    #pragma unroll
    for (int h = 0; h < 4; h++) { int i = tid + (h << 8); A[i] = row[i]; }
    #pragma unroll
    for (int h = 0; h < 2; h++) {
        int j = tid + (h << 8);
        float sn, cn;
        __sincosf(6.283185307179586f * (float)j * (1.0f / 1024.0f), &sn, &cn);
        W[j] = make_float2(cn, sn);
    }

    fft1024_inv(A, Bb, W, tid);

    float a2 = apodf(xo2);
    #pragma unroll
    for (int h = 0; h < 2; h++) {
        int xo1 = tid + (h << 8);
        int x1  = (xo1 + 768) & 1023;
        float a1 = apodf(xo1);
        out[((size_t)b * 512 + xo1) * 512 + xo2] = A[x1].x / (a1 * a2);
    }
}

// ---------- host launch ----------
extern "C" void kernel_launch(void* const* d_in, const int* in_sizes, int n_in,
                              void* d_out, int out_size, void* d_ws, size_t ws_size,
                              hipStream_t stream)
{
    const float* yr  = (const float*)d_in[0];
    const float* yi  = (const float*)d_in[1];
    const float* uv  = (const float*)d_in[2];
    const float* wts = (const float*)d_in[3];

    int M = in_sizes[3];

    const size_t gridBytes = (size_t)KGRID * KGRID * NB * sizeof(float2);  // 64 MB planar
    float2* gP = (float2*)d_ws;
    char*   p2 = (char*)d_ws + gridBytes;
    float2* T  = (float2*)p2;                        // 32 MB, pass1/pass2 only
    // bin-phase scratch ALIASES T (temporally disjoint with pass1/pass2):
    int*    cnt  = (int*)p2;                         // 16 KB
    int*    list = (int*)(p2 + (64u << 10));         // 3 MB   (4096*192*4)
    float2* yP   = (float2*)(p2 + (4u << 20));       // 12.8 MB @ +4MB
    float4* uvw  = (float4*)(p2 + (20u << 20));      // 3.2 MB @ +20MB

    hipMemsetAsync(cnt, 0, NBIN * sizeof(int), stream);
    prep_kernel<<<dim3((M + 255) / 256), dim3(256), 0, stream>>>(
        yr, yi, uv, wts, yP, uvw, cnt, list, M);
    grid_tile<<<dim3(NBIN / 4), dim3(256), 0, stream>>>(
        uvw, (const float4*)yP, cnt, list, gP);
    fft_pass1<<<dim3(NB * 256), dim3(256), 0, stream>>>(gP, T);
    fft_pass2<<<dim3(NB * 512), dim3(256), 0, stream>>>(T, (float*)d_out);
}

// Round 10
// 252.421 us; speedup vs baseline: 3.4590x; 1.3880x over previous
//
#include <hip/hip_runtime.h>
#include <math.h>

#define KGRID 1024
#define NIMG  512
#define JW    6
#define BETAF 14.04f   // 2.34 * J
#define NB    8        // batch count (fixed by problem)
#define NBIN  8192     // 128 x-tiles (TX=8) x 64 y-tiles (TY=16)
#define CAP   128      // max point-entries per bin (mean ~52 with gather halo)

// ---------- Kaiser-Bessel I0 (Abramowitz & Stegun 9.8.1 / 9.8.2, ~2e-7 rel) ----------
__device__ __forceinline__ float i0f_dev(float x) {
    float ax = fabsf(x);
    if (ax < 3.75f) {
        float z = ax * (1.0f / 3.75f);
        z = z * z;
        return 1.0f + z * (3.5156229f + z * (3.0899424f + z * (1.2067492f +
               z * (0.2659732f + z * (0.0360768f + z * 0.0045813f)))));
    } else {
        float z = 3.75f / ax;
        float p = 0.39894228f + z * (0.01328592f + z * (0.00225319f + z * (-0.00157565f +
                  z * (0.00916281f + z * (-0.02057706f + z * (0.02635537f +
                  z * (-0.01647633f + z * 0.00392377f)))))));
        return expf(ax) * rsqrtf(ax) * p;
    }
}

// ---------- Phase 0: precompute weights/meta (64B line) + y lines + gather-bin ----------
// pnt line slots (lane&15 load in grid_tile): [0..5]=wx*sc, [6]=x0 bits, [7]=y0 bits,
// [8..13]=wy, [14]=[15]=0  (zero slots double as clamp targets).
__global__ __launch_bounds__(256) void prep_kernel(
    const float* __restrict__ yr, const float* __restrict__ yi,
    const float* __restrict__ uv, const float* __restrict__ wts,
    float4* __restrict__ yF4, float4* __restrict__ pnt,
    int* __restrict__ cnt, int* __restrict__ list, int M)
{
    int m = blockIdx.x * 256 + threadIdx.x;
    if (m >= M) return;
    float inv = 1.0f / i0f_dev(BETAF);
    float s2 = inv * inv;

    #pragma unroll
    for (int bp = 0; bp < 4; bp++) {
        int b0 = 2 * bp;
        yF4[(size_t)m * 4 + bp] = make_float4(
            yr[(size_t)b0 * M + m],       yi[(size_t)b0 * M + m],
            yr[(size_t)(b0 + 1) * M + m], yi[(size_t)(b0 + 1) * M + m]);
    }

    float u = uv[2 * m], v = uv[2 * m + 1];
    float sc = wts[m] * s2;
    const float c2g = (float)KGRID / 6.283185307179586f;
    float kx = u * c2g, ky = v * c2g;
    float kmx = floorf(kx - 3.0f), kmy = floorf(ky - 3.0f);
    int x0m = (((int)kmx + 1) + 1024) & 1023;
    int y0m = (((int)kmy + 1) + 1024) & 1023;

    float wx[JW], wy[JW];
    #pragma unroll
    for (int j = 0; j < JW; j++) {
        float dx = kx - kmx - 1.0f - (float)j;
        float rx = dx * (1.0f / 3.0f);
        float ax = fmaxf(1.0f - rx * rx, 0.0f);
        wx[j] = i0f_dev(BETAF * sqrtf(ax)) * sc;
        float dy = ky - kmy - 1.0f - (float)j;
        float ry = dy * (1.0f / 3.0f);
        float ay = fmaxf(1.0f - ry * ry, 0.0f);
        wy[j] = i0f_dev(BETAF * sqrtf(ay));
    }

    float4* p = pnt + (size_t)m * 4;
    p[0] = make_float4(wx[0], wx[1], wx[2], wx[3]);
    p[1] = make_float4(wx[4], wx[5], __int_as_float(x0m), __int_as_float(y0m));
    p[2] = make_float4(wy[0], wy[1], wy[2], wy[3]);
    p[3] = make_float4(wy[4], wy[5], 0.0f, 0.0f);

    // gather-bin: TX=8 (push next x-tile if offset>=3), TY=16 (offset>=11)
    int txA = x0m >> 3, txB = (txA + 1) & 127;
    int tyA = y0m >> 4, tyB = (tyA + 1) & 63;
    bool bx = (x0m & 7) >= 3;
    bool by = (y0m & 15) >= 11;

    #define PUSH(tx, ty) { int bin = ((tx) << 6) | (ty);                 \
                           int slot = atomicAdd(&cnt[bin], 1);           \
                           if (slot < CAP) list[bin * CAP + slot] = m; }
    PUSH(txA, tyA);
    if (by)  PUSH(txA, tyB);
    if (bx) { PUSH(txB, tyA); if (by) PUSH(txB, tyB); }
    #undef PUSH
}

// ---------- Phase B: gather-gridding, register accumulation, zero LDS ----------
// One wave per 8x16 tile. Lane l: ly = l>>2, bp = l&3 (batches 2bp,2bp+1).
// acc[8] float4 = lane's 8 lx cells x 2 batches. Weights precomputed: one 64B
// line/point; wy via one ds_bpermute (clamped to zero slots), wx via readlane
// with scalar clamp; fma uses the SGPR wx operand directly.
__global__ __launch_bounds__(256, 4) void grid_tile(
    const float* __restrict__ pnt, const float4* __restrict__ yF4,
    const int* __restrict__ cnt, const int* __restrict__ list,
    float2* __restrict__ gP)
{
    int lane = threadIdx.x & 63;
    int wid  = threadIdx.x >> 6;
    int tile = blockIdx.x * 4 + wid;
    int tx0 = (tile >> 6) << 3;     // 128 x-tiles, TX=8
    int ty0 = (tile & 63) << 4;     // 64 y-tiles, TY=16

    int ly = lane >> 2;
    int bp = lane & 3;
    int slot = lane & 15;

    float4 acc[8];
    #pragma unroll
    for (int i = 0; i < 8; i++) acc[i] = make_float4(0.f, 0.f, 0.f, 0.f);

    int n = cnt[tile]; if (n > CAP) n = CAP;
    const int* lst = list + tile * CAP;

    // preload the whole index list into 2 VGPRs (CAP=128)
    int lv0 = (lane < n) ? lst[lane] : 0;
    int lv1 = (64 + lane < n) ? lst[64 + lane] : 0;

    #define FETCH_M(i) __builtin_amdgcn_readlane(((i) < 64) ? lv0 : lv1, (i) & 63)

    float  pw0 = 0.f, pw1 = 0.f;
    float4 ya0 = make_float4(0.f,0.f,0.f,0.f), ya1 = ya0;
    if (n > 0) { int m = FETCH_M(0); pw0 = pnt[(size_t)m * 16 + slot]; ya0 = yF4[(size_t)m * 4 + bp]; }
    if (n > 1) { int m = FETCH_M(1); pw1 = pnt[(size_t)m * 16 + slot]; ya1 = yF4[(size_t)m * 4 + bp]; }

    for (int i = 0; i < n; i++) {
        float  pwN = 0.f;
        float4 yaN = make_float4(0.f,0.f,0.f,0.f);
        if (i + 2 < n) {
            int m = FETCH_M(i + 2);
            pwN = pnt[(size_t)m * 16 + slot];
            yaN = yF4[(size_t)m * 4 + bp];
        }

        // meta (scalar) — readlane already returns the raw int bits; NO extra cast
        int x0 = __builtin_amdgcn_readlane(__float_as_int(pw0), 6);
        int y0 = __builtin_amdgcn_readlane(__float_as_int(pw0), 7);
        int xr = (x0 - tx0) & 1023;
        int yrS = (y0 - ty0) & 1023;

        // per-lane wy: idx 8+min(j2,7); slots 14/15 are stored zeros
        int j2 = (ly - yrS) & 1023;
        int idxy = (j2 < 7 ? j2 : 7) + 8;
        float wyl = __int_as_float(__builtin_amdgcn_ds_bpermute(idxy << 2, __float_as_int(pw0)));

        float4 ys = make_float4(ya0.x * wyl, ya0.y * wyl, ya0.z * wyl, ya0.w * wyl);

        #pragma unroll
        for (int lx = 0; lx < 8; lx++) {
            int j1 = (lx - xr) & 1023;                 // scalar
            int idx = (j1 < 6) ? j1 : 15;              // slot 15 = 0
            float wx = __int_as_float(__builtin_amdgcn_readlane(__float_as_int(pw0), idx));
            acc[lx].x = fmaf(wx, ys.x, acc[lx].x);
            acc[lx].y = fmaf(wx, ys.y, acc[lx].y);
            acc[lx].z = fmaf(wx, ys.z, acc[lx].z);
            acc[lx].w = fmaf(wx, ys.w, acc[lx].w);
        }

        pw0 = pw1; ya0 = ya1;
        pw1 = pwN; ya1 = yaN;
    }
    #undef FETCH_M

    // flush to planar grid (gather covers every cell exactly once)
    int b0 = bp << 1;
    #pragma unroll
    for (int lx = 0; lx < 8; lx++) {
        size_t rowoff = ((size_t)(tx0 + lx) << 10) + (size_t)(ty0 + ly);
        gP[((size_t)b0 << 20) + rowoff]       = make_float2(acc[lx].x, acc[lx].y);
        gP[((size_t)(b0 + 1) << 20) + rowoff] = make_float2(acc[lx].z, acc[lx].w);
    }
}

// ---------- Stockham radix-2 1024-pt inverse (e^{+i}) FFT in LDS ----------
__device__ __forceinline__ void fft1024_inv(float2* X, float2* Y, const float2* W, int tid)
{
    float2* src = X;
    float2* dst = Y;
    #pragma unroll
    for (int stage = 0; stage < 10; stage++) {
        const int s = 1 << stage;
        __syncthreads();
        #pragma unroll
        for (int h = 0; h < 2; h++) {
            int t  = tid + (h << 8);
            int sp = t & ~(s - 1);
            float2 c0 = src[t];
            float2 c1 = src[t + 512];
            float2 sum = make_float2(c0.x + c1.x, c0.y + c1.y);
            float2 dif = make_float2(c0.x - c1.x, c0.y - c1.y);
            float2 w = W[sp];
            dst[t + sp]     = sum;
            dst[t + sp + s] = make_float2(w.x * dif.x - w.y * dif.y,
                                          w.x * dif.y + w.y * dif.x);
        }
        float2* tmp = src; src = dst; dst = tmp;
    }
    __syncthreads();
}

// ---------- Pass 1: rows (k2 -> x2) from planar grid, 4 rows/block;
// keep 512 shifted cols; LDS-staged k1-block transpose -> 16B stores ----------
__global__ __launch_bounds__(256) void fft_pass1(const float2* __restrict__ gP,
                                                 float2* __restrict__ T)
{
    __shared__ float2 A[1024];
    __shared__ float2 Bb[1024];
    __shared__ float2 W[512];
    __shared__ float2 R[4][512];

    int blk = blockIdx.x;
    int b   = blk >> 8;
    int k1g = blk & 255;
    int tid = threadIdx.x;

    #pragma unroll
    for (int h = 0; h < 2; h++) {
        int j = tid + (h << 8);
        float sn, cn;
        __sincosf(6.283185307179586f * (float)j * (1.0f / 1024.0f), &sn, &cn);
        W[j] = make_float2(cn, sn);
    }

    for (int r = 0; r < 4; r++) {
        int k1 = (k1g << 2) + r;
        const float2* row = gP + ((size_t)b << 20) + ((size_t)k1 << 10);
        __syncthreads();
        #pragma unroll
        for (int h = 0; h < 4; h++) { int i = tid + (h << 8); A[i] = row[i]; }
        fft1024_inv(A, Bb, W, tid);
        #pragma unroll
        for (int h = 0; h < 2; h++) {
            int xo2 = tid + (h << 8);
            R[r][xo2] = A[(xo2 + 768) & 1023];
        }
    }
    __syncthreads();

    #pragma unroll
    for (int h = 0; h < 2; h++) {
        int xo2 = tid + (h << 8);
        float2 f0 = R[0][xo2], f1 = R[1][xo2], f2 = R[2][xo2], f3 = R[3][xo2];
        float4* d4 = (float4*)(T + (((size_t)b * 512 + xo2) << 10) + (k1g << 2));
        d4[0] = make_float4(f0.x, f0.y, f1.x, f1.y);
        d4[1] = make_float4(f2.x, f2.y, f3.x, f3.y);
    }
}

// ---------- de-apodization (matches _deapod) ----------
__device__ __forceinline__ float apodf(int n) {
    float x  = ((float)n - 256.0f) * (1.0f / 1024.0f);
    float px = 3.14159265358979f * 6.0f * x;
    float t  = BETAF * BETAF - px * px;
    float st = sqrtf(fabsf(t));
    float num = (t > 0.0f) ? sinhf(st) : __sinf(st);
    return num / fmaxf(st, 1e-6f);
}

// ---------- Pass 2: columns (k1 -> x1), fuse shift/crop/real/de-apod ----------
__global__ __launch_bounds__(256) void fft_pass2(const float2* __restrict__ T,
                                                 float* __restrict__ out)
{
    __shared__ float2 A[1024];
    __shared__ float2 Bb[1024];
    __shared__ float2 W[512];

    int blk = blockIdx.x;
    int b   = blk >> 9;
    int xo2 = blk & 511;
    int tid = threadIdx.x;

    const float2* row = T + (((size_t)b * 512 + xo2) << 10);
    #pragma unroll
    for (int h = 0; h < 4; h++) { int i = tid + (h << 8); A[i] = row[i]; }
    #pragma unroll
    for (int h = 0; h < 2; h++) {
        int j = tid + (h << 8);
        float sn, cn;
        __sincosf(6.283185307179586f * (float)j * (1.0f / 1024.0f), &sn, &cn);
        W[j] = make_float2(cn, sn);
    }

    fft1024_inv(A, Bb, W, tid);

    float a2 = apodf(xo2);
    #pragma unroll
    for (int h = 0; h < 2; h++) {
        int xo1 = tid + (h << 8);
        int x1  = (xo1 + 768) & 1023;
        float a1 = apodf(xo1);
        out[((size_t)b * 512 + xo1) * 512 + xo2] = A[x1].x / (a1 * a2);
    }
}

// ---------- host launch ----------
extern "C" void kernel_launch(void* const* d_in, const int* in_sizes, int n_in,
                              void* d_out, int out_size, void* d_ws, size_t ws_size,
                              hipStream_t stream)
{
    const float* yr  = (const float*)d_in[0];
    const float* yi  = (const float*)d_in[1];
    const float* uv  = (const float*)d_in[2];
    const float* wts = (const float*)d_in[3];

    int M = in_sizes[3];

    const size_t gridBytes = (size_t)KGRID * KGRID * NB * sizeof(float2);  // 64 MB planar
    float2* gP = (float2*)d_ws;
    char*   p2 = (char*)d_ws + gridBytes;
    float2* T  = (float2*)p2;                        // 32 MB, pass1/pass2 only
    // bin-phase scratch ALIASES T (temporally disjoint with pass1/pass2):
    int*    cnt  = (int*)p2;                         // 32 KB
    int*    list = (int*)(p2 + (64u << 10));         // 4 MB   (8192*128*4)
    float4* yF4  = (float4*)(p2 + (5u << 20));       // 12.8 MB
    float4* pnt  = (float4*)(p2 + (18u << 20));      // 12.8 MB

    hipMemsetAsync(cnt, 0, NBIN * sizeof(int), stream);
    prep_kernel<<<dim3((M + 255) / 256), dim3(256), 0, stream>>>(
        yr, yi, uv, wts, yF4, pnt, cnt, list, M);
    grid_tile<<<dim3(NBIN / 4), dim3(256), 0, stream>>>(
        (const float*)pnt, (const float4*)yF4, cnt, list, gP);
    fft_pass1<<<dim3(NB * 256), dim3(256), 0, stream>>>(gP, T);
    fft_pass2<<<dim3(NB * 512), dim3(256), 0, stream>>>(T, (float*)d_out);
}

// Round 11
// 249.361 us; speedup vs baseline: 3.5014x; 1.0123x over previous
//
#include <hip/hip_runtime.h>
#include <math.h>

#define KGRID 1024
#define NIMG  512
#define JW    6
#define BETAF 14.04f   // 2.34 * J
#define NB    8        // batch count (fixed by problem)
#define NBIN  8192     // 128 x-tiles (TX=8) x 64 y-tiles (TY=16)
#define CAP   128      // max point-entries per bin (mean ~52 with gather halo)

// ---------- Kaiser-Bessel I0 (Abramowitz & Stegun 9.8.1 / 9.8.2, ~2e-7 rel) ----------
__device__ __forceinline__ float i0f_dev(float x) {
    float ax = fabsf(x);
    if (ax < 3.75f) {
        float z = ax * (1.0f / 3.75f);
        z = z * z;
        return 1.0f + z * (3.5156229f + z * (3.0899424f + z * (1.2067492f +
               z * (0.2659732f + z * (0.0360768f + z * 0.0045813f)))));
    } else {
        float z = 3.75f / ax;
        float p = 0.39894228f + z * (0.01328592f + z * (0.00225319f + z * (-0.00157565f +
                  z * (0.00916281f + z * (-0.02057706f + z * (0.02635537f +
                  z * (-0.01647633f + z * 0.00392377f)))))));
        return expf(ax) * rsqrtf(ax) * p;
    }
}

// ---------- Phase 0: precompute weights/meta (64B line) + y lines + gather-bin ----------
__global__ __launch_bounds__(256) void prep_kernel(
    const float* __restrict__ yr, const float* __restrict__ yi,
    const float* __restrict__ uv, const float* __restrict__ wts,
    float4* __restrict__ yF4, float4* __restrict__ pnt,
    int* __restrict__ cnt, int* __restrict__ list, int M)
{
    int m = blockIdx.x * 256 + threadIdx.x;
    if (m >= M) return;
    float inv = 1.0f / i0f_dev(BETAF);
    float s2 = inv * inv;

    #pragma unroll
    for (int bp = 0; bp < 4; bp++) {
        int b0 = 2 * bp;
        yF4[(size_t)m * 4 + bp] = make_float4(
            yr[(size_t)b0 * M + m],       yi[(size_t)b0 * M + m],
            yr[(size_t)(b0 + 1) * M + m], yi[(size_t)(b0 + 1) * M + m]);
    }

    float u = uv[2 * m], v = uv[2 * m + 1];
    float sc = wts[m] * s2;
    const float c2g = (float)KGRID / 6.283185307179586f;
    float kx = u * c2g, ky = v * c2g;
    float kmx = floorf(kx - 3.0f), kmy = floorf(ky - 3.0f);
    int x0m = (((int)kmx + 1) + 1024) & 1023;
    int y0m = (((int)kmy + 1) + 1024) & 1023;

    float wx[JW], wy[JW];
    #pragma unroll
    for (int j = 0; j < JW; j++) {
        float dx = kx - kmx - 1.0f - (float)j;
        float rx = dx * (1.0f / 3.0f);
        float ax = fmaxf(1.0f - rx * rx, 0.0f);
        wx[j] = i0f_dev(BETAF * sqrtf(ax)) * sc;
        float dy = ky - kmy - 1.0f - (float)j;
        float ry = dy * (1.0f / 3.0f);
        float ay = fmaxf(1.0f - ry * ry, 0.0f);
        wy[j] = i0f_dev(BETAF * sqrtf(ay));
    }

    float4* p = pnt + (size_t)m * 4;
    p[0] = make_float4(wx[0], wx[1], wx[2], wx[3]);
    p[1] = make_float4(wx[4], wx[5], __int_as_float(x0m), __int_as_float(y0m));
    p[2] = make_float4(wy[0], wy[1], wy[2], wy[3]);
    p[3] = make_float4(wy[4], wy[5], 0.0f, 0.0f);

    // gather-bin: TX=8 (push next x-tile if offset>=3), TY=16 (offset>=11)
    int txA = x0m >> 3, txB = (txA + 1) & 127;
    int tyA = y0m >> 4, tyB = (tyA + 1) & 63;
    bool bx = (x0m & 7) >= 3;
    bool by = (y0m & 15) >= 11;

    #define PUSH(tx, ty) { int bin = ((tx) << 6) | (ty);                 \
                           int slot = atomicAdd(&cnt[bin], 1);           \
                           if (slot < CAP) list[bin * CAP + slot] = m; }
    PUSH(txA, tyA);
    if (by)  PUSH(txA, tyB);
    if (bx) { PUSH(txB, tyA); if (by) PUSH(txB, tyB); }
    #undef PUSH
}

// ---------- Phase B: gather-gridding, register accumulation, zero LDS ----------
__global__ __launch_bounds__(256, 4) void grid_tile(
    const float* __restrict__ pnt, const float4* __restrict__ yF4,
    const int* __restrict__ cnt, const int* __restrict__ list,
    float2* __restrict__ gP)
{
    int lane = threadIdx.x & 63;
    int wid  = threadIdx.x >> 6;
    int tile = blockIdx.x * 4 + wid;
    int tx0 = (tile >> 6) << 3;     // 128 x-tiles, TX=8
    int ty0 = (tile & 63) << 4;     // 64 y-tiles, TY=16

    int ly = lane >> 2;
    int bp = lane & 3;
    int slot = lane & 15;

    float4 acc[8];
    #pragma unroll
    for (int i = 0; i < 8; i++) acc[i] = make_float4(0.f, 0.f, 0.f, 0.f);

    int n = cnt[tile]; if (n > CAP) n = CAP;
    const int* lst = list + tile * CAP;

    int lv0 = (lane < n) ? lst[lane] : 0;
    int lv1 = (64 + lane < n) ? lst[64 + lane] : 0;

    #define FETCH_M(i) __builtin_amdgcn_readlane(((i) < 64) ? lv0 : lv1, (i) & 63)

    float  pw0 = 0.f, pw1 = 0.f;
    float4 ya0 = make_float4(0.f,0.f,0.f,0.f), ya1 = ya0;
    if (n > 0) { int m = FETCH_M(0); pw0 = pnt[(size_t)m * 16 + slot]; ya0 = yF4[(size_t)m * 4 + bp]; }
    if (n > 1) { int m = FETCH_M(1); pw1 = pnt[(size_t)m * 16 + slot]; ya1 = yF4[(size_t)m * 4 + bp]; }

    for (int i = 0; i < n; i++) {
        float  pwN = 0.f;
        float4 yaN = make_float4(0.f,0.f,0.f,0.f);
        if (i + 2 < n) {
            int m = FETCH_M(i + 2);
            pwN = pnt[(size_t)m * 16 + slot];
            yaN = yF4[(size_t)m * 4 + bp];
        }

        int x0 = __builtin_amdgcn_readlane(__float_as_int(pw0), 6);
        int y0 = __builtin_amdgcn_readlane(__float_as_int(pw0), 7);
        int xr = (x0 - tx0) & 1023;
        int yrS = (y0 - ty0) & 1023;

        int j2 = (ly - yrS) & 1023;
        int idxy = (j2 < 7 ? j2 : 7) + 8;
        float wyl = __int_as_float(__builtin_amdgcn_ds_bpermute(idxy << 2, __float_as_int(pw0)));

        float4 ys = make_float4(ya0.x * wyl, ya0.y * wyl, ya0.z * wyl, ya0.w * wyl);

        #pragma unroll
        for (int lx = 0; lx < 8; lx++) {
            int j1 = (lx - xr) & 1023;
            int idx = (j1 < 6) ? j1 : 15;
            float wx = __int_as_float(__builtin_amdgcn_readlane(__float_as_int(pw0), idx));
            acc[lx].x = fmaf(wx, ys.x, acc[lx].x);
            acc[lx].y = fmaf(wx, ys.y, acc[lx].y);
            acc[lx].z = fmaf(wx, ys.z, acc[lx].z);
            acc[lx].w = fmaf(wx, ys.w, acc[lx].w);
        }

        pw0 = pw1; ya0 = ya1;
        pw1 = pwN; ya1 = yaN;
    }
    #undef FETCH_M

    int b0 = bp << 1;
    #pragma unroll
    for (int lx = 0; lx < 8; lx++) {
        size_t rowoff = ((size_t)(tx0 + lx) << 10) + (size_t)(ty0 + ly);
        gP[((size_t)b0 << 20) + rowoff]       = make_float2(acc[lx].x, acc[lx].y);
        gP[((size_t)(b0 + 1) << 20) + rowoff] = make_float2(acc[lx].z, acc[lx].w);
    }
}

// ---------- Hermitian symmetrize + batch-pair pack ----------
// real(IDFT(g)) = IDFT(h), h(k) = (g(k)+conj(g(-k)))/2 (Hermitian -> real IDFT).
// zP[p] = h_{2p} + i*h_{2p+1}: IDFT(zP[p]) = R_{2p} + i*R_{2p+1}, both real.
__global__ __launch_bounds__(256) void sym_pack(const float2* __restrict__ gP,
                                                float2* __restrict__ zP)
{
    int blk = blockIdx.x;
    int p   = blk >> 10;          // 4 packed planes
    int k1  = blk & 1023;
    int tid = threadIdx.x;
    int nk1 = (1024 - k1) & 1023;

    const float2* rA  = gP + ((size_t)(2 * p)     << 20) + ((size_t)k1  << 10);
    const float2* rAn = gP + ((size_t)(2 * p)     << 20) + ((size_t)nk1 << 10);
    const float2* rB  = gP + ((size_t)(2 * p + 1) << 20) + ((size_t)k1  << 10);
    const float2* rBn = gP + ((size_t)(2 * p + 1) << 20) + ((size_t)nk1 << 10);
    float2* zrow = zP + ((size_t)p << 20) + ((size_t)k1 << 10);

    #pragma unroll
    for (int h = 0; h < 4; h++) {
        int k2  = tid + (h << 8);
        int nk2 = (1024 - k2) & 1023;
        float2 va  = rA[k2];
        float2 van = rAn[nk2];
        float2 vb  = rB[k2];
        float2 vbn = rBn[nk2];
        float zx = 0.5f * (va.x + van.x) - 0.5f * (vb.y - vbn.y);
        float zy = 0.5f * (va.y - van.y) + 0.5f * (vb.x + vbn.x);
        zrow[k2] = make_float2(zx, zy);
    }
}

// ---------- Stockham radix-2 1024-pt inverse (e^{+i}) FFT in LDS ----------
__device__ __forceinline__ void fft1024_inv(float2* X, float2* Y, const float2* W, int tid)
{
    float2* src = X;
    float2* dst = Y;
    #pragma unroll
    for (int stage = 0; stage < 10; stage++) {
        const int s = 1 << stage;
        __syncthreads();
        #pragma unroll
        for (int h = 0; h < 2; h++) {
            int t  = tid + (h << 8);
            int sp = t & ~(s - 1);
            float2 c0 = src[t];
            float2 c1 = src[t + 512];
            float2 sum = make_float2(c0.x + c1.x, c0.y + c1.y);
            float2 dif = make_float2(c0.x - c1.x, c0.y - c1.y);
            float2 w = W[sp];
            dst[t + sp]     = sum;
            dst[t + sp + s] = make_float2(w.x * dif.x - w.y * dif.y,
                                          w.x * dif.y + w.y * dif.x);
        }
        float2* tmp = src; src = dst; dst = tmp;
    }
    __syncthreads();
}

// ---------- Pass 1: rows (k2 -> x2) of packed planes, 4 rows/block;
// keep 512 shifted cols; LDS-staged k1-block transpose -> 16B stores ----------
__global__ __launch_bounds__(256) void fft_pass1(const float2* __restrict__ zP,
                                                 float2* __restrict__ T)
{
    __shared__ float2 A[1024];
    __shared__ float2 Bb[1024];
    __shared__ float2 W[512];
    __shared__ float2 R[4][512];

    int blk = blockIdx.x;
    int p   = blk >> 8;          // 4 packed planes
    int k1g = blk & 255;
    int tid = threadIdx.x;

    #pragma unroll
    for (int h = 0; h < 2; h++) {
        int j = tid + (h << 8);
        float sn, cn;
        __sincosf(6.283185307179586f * (float)j * (1.0f / 1024.0f), &sn, &cn);
        W[j] = make_float2(cn, sn);
    }

    for (int r = 0; r < 4; r++) {
        int k1 = (k1g << 2) + r;
        const float2* row = zP + ((size_t)p << 20) + ((size_t)k1 << 10);
        __syncthreads();
        #pragma unroll
        for (int h = 0; h < 4; h++) { int i = tid + (h << 8); A[i] = row[i]; }
        fft1024_inv(A, Bb, W, tid);
        #pragma unroll
        for (int h = 0; h < 2; h++) {
            int xo2 = tid + (h << 8);
            R[r][xo2] = A[(xo2 + 768) & 1023];
        }
    }
    __syncthreads();

    #pragma unroll
    for (int h = 0; h < 2; h++) {
        int xo2 = tid + (h << 8);
        float2 f0 = R[0][xo2], f1 = R[1][xo2], f2 = R[2][xo2], f3 = R[3][xo2];
        float4* d4 = (float4*)(T + (((size_t)p * 512 + xo2) << 10) + (k1g << 2));
        d4[0] = make_float4(f0.x, f0.y, f1.x, f1.y);
        d4[1] = make_float4(f2.x, f2.y, f3.x, f3.y);
    }
}

// ---------- de-apodization (matches _deapod) ----------
__device__ __forceinline__ float apodf(int n) {
    float x  = ((float)n - 256.0f) * (1.0f / 1024.0f);
    float px = 3.14159265358979f * 6.0f * x;
    float t  = BETAF * BETAF - px * px;
    float st = sqrtf(fabsf(t));
    float num = (t > 0.0f) ? sinhf(st) : __sinf(st);
    return num / fmaxf(st, 1e-6f);
}

// ---------- Pass 2: columns (k1 -> x1) of packed planes, 4 cols/block;
// real part -> batch 2p, imag part -> batch 2p+1; coalesced float4 stores ----------
__global__ __launch_bounds__(256) void fft_pass2(const float2* __restrict__ T,
                                                 float* __restrict__ out)
{
    __shared__ float2 A[1024];
    __shared__ float2 Bb[1024];
    __shared__ float2 W[512];
    __shared__ float2 R[4][512];

    int blk = blockIdx.x;
    int p   = blk >> 7;          // 4 packed planes
    int xg  = blk & 127;         // 128 groups of 4 columns
    int tid = threadIdx.x;

    #pragma unroll
    for (int h = 0; h < 2; h++) {
        int j = tid + (h << 8);
        float sn, cn;
        __sincosf(6.283185307179586f * (float)j * (1.0f / 1024.0f), &sn, &cn);
        W[j] = make_float2(cn, sn);
    }

    float a2[4];
    #pragma unroll
    for (int r = 0; r < 4; r++) a2[r] = apodf((xg << 2) + r);

    for (int r = 0; r < 4; r++) {
        int xo2 = (xg << 2) + r;
        const float2* row = T + (((size_t)p * 512 + xo2) << 10);
        __syncthreads();
        #pragma unroll
        for (int h = 0; h < 4; h++) { int i = tid + (h << 8); A[i] = row[i]; }
        fft1024_inv(A, Bb, W, tid);
        #pragma unroll
        for (int h = 0; h < 2; h++) {
            int xo1 = tid + (h << 8);
            float2 v = A[(xo1 + 768) & 1023];
            R[r][xo1] = make_float2(v.x / a2[r], v.y / a2[r]);
        }
    }
    __syncthreads();

    int b0 = 2 * p;
    #pragma unroll
    for (int h = 0; h < 2; h++) {
        int xo1 = tid + (h << 8);
        float inva1 = 1.0f / apodf(xo1);
        float2 f0 = R[0][xo1], f1 = R[1][xo1], f2 = R[2][xo1], f3 = R[3][xo1];
        float4* o0 = (float4*)(out + (((size_t)b0 * 512 + xo1) << 9) + (xg << 2));
        float4* o1 = (float4*)(out + (((size_t)(b0 + 1) * 512 + xo1) << 9) + (xg << 2));
        *o0 = make_float4(f0.x * inva1, f1.x * inva1, f2.x * inva1, f3.x * inva1);
        *o1 = make_float4(f0.y * inva1, f1.y * inva1, f2.y * inva1, f3.y * inva1);
    }
}

// ---------- host launch ----------
extern "C" void kernel_launch(void* const* d_in, const int* in_sizes, int n_in,
                              void* d_out, int out_size, void* d_ws, size_t ws_size,
                              hipStream_t stream)
{
    const float* yr  = (const float*)d_in[0];
    const float* yi  = (const float*)d_in[1];
    const float* uv  = (const float*)d_in[2];
    const float* wts = (const float*)d_in[3];

    int M = in_sizes[3];

    // ws layout (96 MB, phase-aliased):
    //  [0,64)MB : gP (8 planar batch grids) during grid phase;
    //             first 16 MB reused as T during pass1/pass2 (gP dead then)
    //  [64,96)MB: bin scratch (cnt/list/yF4/pnt) during prep/grid_tile;
    //             then zP (4 packed planes, 32 MB) written by sym_pack
    float2* gP = (float2*)d_ws;
    float2* T  = (float2*)d_ws;                      // aliases gP[0,16MB)
    char*   p2 = (char*)d_ws + ((size_t)64 << 20);
    float2* zP = (float2*)p2;                        // 32 MB
    int*    cnt  = (int*)p2;                         // 32 KB
    int*    list = (int*)(p2 + (64u << 10));         // 4 MB
    float4* yF4  = (float4*)(p2 + (5u << 20));       // 12.8 MB
    float4* pnt  = (float4*)(p2 + (18u << 20));      // 12.8 MB

    hipMemsetAsync(cnt, 0, NBIN * sizeof(int), stream);
    prep_kernel<<<dim3((M + 255) / 256), dim3(256), 0, stream>>>(
        yr, yi, uv, wts, yF4, pnt, cnt, list, M);
    grid_tile<<<dim3(NBIN / 4), dim3(256), 0, stream>>>(
        (const float*)pnt, (const float4*)yF4, cnt, list, gP);
    sym_pack<<<dim3(4 * 1024), dim3(256), 0, stream>>>(gP, zP);
    fft_pass1<<<dim3(4 * 256), dim3(256), 0, stream>>>(zP, T);
    fft_pass2<<<dim3(4 * 128), dim3(256), 0, stream>>>(T, (float*)d_out);
}

// Round 12
// 189.281 us; speedup vs baseline: 4.6128x; 1.3174x over previous
//
#include <hip/hip_runtime.h>
#include <math.h>

#define KGRID 1024
#define NIMG  512
#define JW    6
#define BETAF 14.04f   // 2.34 * J
#define NB    8        // batch count (fixed by problem)
#define TS    8        // tile side (8x8, lane=cell)
#define NBIN  16384    // 128 x 128 tiles
#define CAP   96       // max entries per bin (mean ~33, uniform uv)

// ---------- Kaiser-Bessel I0 (Abramowitz & Stegun 9.8.1 / 9.8.2, ~2e-7 rel) ----------
__device__ __forceinline__ float i0f_dev(float x) {
    float ax = fabsf(x);
    if (ax < 3.75f) {
        float z = ax * (1.0f / 3.75f);
        z = z * z;
        return 1.0f + z * (3.5156229f + z * (3.0899424f + z * (1.2067492f +
               z * (0.2659732f + z * (0.0360768f + z * 0.0045813f)))));
    } else {
        float z = 3.75f / ax;
        float p = 0.39894228f + z * (0.01328592f + z * (0.00225319f + z * (-0.00157565f +
                  z * (0.00916281f + z * (-0.02057706f + z * (0.02635537f +
                  z * (-0.01647633f + z * 0.00392377f)))))));
        return expf(ax) * rsqrtf(ax) * p;
    }
}

// ---------- Phase 0: precompute weights/meta + y lines + gather-bin (8x8 tiles) ----------
// pnt line slots: [0..5]=wx*sc, [6]=x0 bits, [7]=y0 bits, [8..13]=wy, [14]=[15]=0.
// Entry m=M is an all-zero dummy line (pipeline padding).
__global__ __launch_bounds__(256) void prep_kernel(
    const float* __restrict__ yr, const float* __restrict__ yi,
    const float* __restrict__ uv, const float* __restrict__ wts,
    float4* __restrict__ yF4, float4* __restrict__ pnt,
    int* __restrict__ cnt, int* __restrict__ list, int M)
{
    int m = blockIdx.x * 256 + threadIdx.x;
    if (m >= M) return;

    if (m == 0) {   // dummy point at index M: zero weights, zero y
        float4 z = make_float4(0.f, 0.f, 0.f, 0.f);
        #pragma unroll
        for (int q = 0; q < 4; q++) { pnt[(size_t)M * 4 + q] = z; yF4[(size_t)M * 4 + q] = z; }
    }

    float inv = 1.0f / i0f_dev(BETAF);
    float s2 = inv * inv;

    #pragma unroll
    for (int bp = 0; bp < 4; bp++) {
        int b0 = 2 * bp;
        yF4[(size_t)m * 4 + bp] = make_float4(
            yr[(size_t)b0 * M + m],       yi[(size_t)b0 * M + m],
            yr[(size_t)(b0 + 1) * M + m], yi[(size_t)(b0 + 1) * M + m]);
    }

    float u = uv[2 * m], v = uv[2 * m + 1];
    float sc = wts[m] * s2;
    const float c2g = (float)KGRID / 6.283185307179586f;
    float kx = u * c2g, ky = v * c2g;
    float kmx = floorf(kx - 3.0f), kmy = floorf(ky - 3.0f);
    int x0m = (((int)kmx + 1) + 1024) & 1023;
    int y0m = (((int)kmy + 1) + 1024) & 1023;

    float wx[JW], wy[JW];
    #pragma unroll
    for (int j = 0; j < JW; j++) {
        float dx = kx - kmx - 1.0f - (float)j;
        float rx = dx * (1.0f / 3.0f);
        float ax = fmaxf(1.0f - rx * rx, 0.0f);
        wx[j] = i0f_dev(BETAF * sqrtf(ax)) * sc;
        float dy = ky - kmy - 1.0f - (float)j;
        float ry = dy * (1.0f / 3.0f);
        float ay = fmaxf(1.0f - ry * ry, 0.0f);
        wy[j] = i0f_dev(BETAF * sqrtf(ay));
    }

    float4* p = pnt + (size_t)m * 4;
    p[0] = make_float4(wx[0], wx[1], wx[2], wx[3]);
    p[1] = make_float4(wx[4], wx[5], __int_as_float(x0m), __int_as_float(y0m));
    p[2] = make_float4(wy[0], wy[1], wy[2], wy[3]);
    p[3] = make_float4(wy[4], wy[5], 0.0f, 0.0f);

    // gather-bin (8x8): footprint 6 wide crosses next tile iff in-tile offset >= 3
    int txA = x0m >> 3, txB = (txA + 1) & 127;
    int tyA = y0m >> 3, tyB = (tyA + 1) & 127;
    bool bx = (x0m & 7) >= 3;
    bool by = (y0m & 7) >= 3;

    #define PUSH(tx, ty) { int bin = ((tx) << 7) | (ty);                 \
                           int slot = atomicAdd(&cnt[bin], 1);           \
                           if (slot < CAP) list[bin * CAP + slot] = m; }
    PUSH(txA, tyA);
    if (by)  PUSH(txA, tyB);
    if (bx) { PUSH(txB, tyA); if (by) PUSH(txB, tyB); }
    #undef PUSH
}

// ---------- Phase B: gather-gridding, lane=cell, register accumulation ----------
// One wave per 8x8 tile. Lane l: lx=l>>3, ly=l&7 -> one cell; acc = 8 batches
// (float2) = 16 VGPR. Per point: one w = wx[j1]*wy[j2] via 2 ds_bpermute from
// the lane-sliced 16-float weight line; 16 fma with wave-uniform y scalars
// (m is readlane-uniform -> s_load). Dummy point m=M (zero line) pads the
// pipeline -> branch-free inner loop.
__global__ __launch_bounds__(256) void grid_tile(
    const float* __restrict__ pnt1, const float4* __restrict__ yF4,
    const int* __restrict__ cnt, const int* __restrict__ list,
    float2* __restrict__ gP, int M)
{
    int lane = threadIdx.x & 63;
    int wid  = threadIdx.x >> 6;
    int tile = blockIdx.x * 4 + wid;
    int tx0 = (tile >> 7) << 3;
    int ty0 = (tile & 127) << 3;
    int lx = lane >> 3, ly = lane & 7;
    int slot = lane & 15;

    float2 acc[NB];
    #pragma unroll
    for (int b = 0; b < NB; b++) acc[b] = make_float2(0.f, 0.f);

    int n = cnt[tile]; if (n > CAP) n = CAP;
    const int* lst = list + tile * CAP;

    // preload index list into 2 VGPRs (slots beyond n -> dummy M)
    int lv0 = (lane < n) ? lst[lane] : M;
    int lv1 = (64 + lane < n && 64 + lane < CAP) ? lst[64 + lane] : M;

    #define FETCH_M(i) __builtin_amdgcn_readlane(((i) < 64) ? lv0 : lv1, (i) & 63)

    int   mA = FETCH_M(0), mB = FETCH_M(1);
    float pwA = pnt1[(size_t)mA * 16 + slot];
    float pwB = pnt1[(size_t)mB * 16 + slot];
    float4 yA0 = yF4[(size_t)mA * 4 + 0], yA1 = yF4[(size_t)mA * 4 + 1],
           yA2 = yF4[(size_t)mA * 4 + 2], yA3 = yF4[(size_t)mA * 4 + 3];
    float4 yB0 = yF4[(size_t)mB * 4 + 0], yB1 = yF4[(size_t)mB * 4 + 1],
           yB2 = yF4[(size_t)mB * 4 + 2], yB3 = yF4[(size_t)mB * 4 + 3];

    for (int i = 0; i < n; i++) {
        int mC = FETCH_M(i + 2);
        float pwC = pnt1[(size_t)mC * 16 + slot];
        float4 yC0 = yF4[(size_t)mC * 4 + 0], yC1 = yF4[(size_t)mC * 4 + 1],
               yC2 = yF4[(size_t)mC * 4 + 2], yC3 = yF4[(size_t)mC * 4 + 3];

        int pwb = __float_as_int(pwA);
        int x0 = __builtin_amdgcn_readlane(pwb, 6);
        int y0 = __builtin_amdgcn_readlane(pwb, 7);
        int j1 = (tx0 + lx - x0) & 1023;
        int j2 = (ty0 + ly - y0) & 1023;
        int i1 = (j1 < 6) ? j1 : 15;            // slot 15 = 0
        int i2 = (j2 < 6) ? (j2 + 8) : 14;      // slot 14 = 0
        float wx = __int_as_float(__builtin_amdgcn_ds_bpermute(i1 << 2, pwb));
        float wy = __int_as_float(__builtin_amdgcn_ds_bpermute(i2 << 2, pwb));
        float w = wx * wy;

        acc[0].x = fmaf(w, yA0.x, acc[0].x); acc[0].y = fmaf(w, yA0.y, acc[0].y);
        acc[1].x = fmaf(w, yA0.z, acc[1].x); acc[1].y = fmaf(w, yA0.w, acc[1].y);
        acc[2].x = fmaf(w, yA1.x, acc[2].x); acc[2].y = fmaf(w, yA1.y, acc[2].y);
        acc[3].x = fmaf(w, yA1.z, acc[3].x); acc[3].y = fmaf(w, yA1.w, acc[3].y);
        acc[4].x = fmaf(w, yA2.x, acc[4].x); acc[4].y = fmaf(w, yA2.y, acc[4].y);
        acc[5].x = fmaf(w, yA2.z, acc[5].x); acc[5].y = fmaf(w, yA2.w, acc[5].y);
        acc[6].x = fmaf(w, yA3.x, acc[6].x); acc[6].y = fmaf(w, yA3.y, acc[6].y);
        acc[7].x = fmaf(w, yA3.z, acc[7].x); acc[7].y = fmaf(w, yA3.w, acc[7].y);

        pwA = pwB; yA0 = yB0; yA1 = yB1; yA2 = yB2; yA3 = yB3;
        pwB = pwC; yB0 = yC0; yB1 = yC1; yB2 = yC2; yB3 = yC3;
    }
    #undef FETCH_M

    // flush: tiles partition the grid -> every cell written exactly once
    size_t cell = ((size_t)(tx0 + lx) << 10) + (size_t)(ty0 + ly);
    #pragma unroll
    for (int b = 0; b < NB; b++)
        gP[((size_t)b << 20) + cell] = acc[b];
}

// ---------- Stockham radix-2 1024-pt inverse (e^{+i}) FFT in LDS ----------
__device__ __forceinline__ void fft1024_inv(float2* X, float2* Y, const float2* W, int tid)
{
    float2* src = X;
    float2* dst = Y;
    #pragma unroll
    for (int stage = 0; stage < 10; stage++) {
        const int s = 1 << stage;
        __syncthreads();
        #pragma unroll
        for (int h = 0; h < 2; h++) {
            int t  = tid + (h << 8);
            int sp = t & ~(s - 1);
            float2 c0 = src[t];
            float2 c1 = src[t + 512];
            float2 sum = make_float2(c0.x + c1.x, c0.y + c1.y);
            float2 dif = make_float2(c0.x - c1.x, c0.y - c1.y);
            float2 w = W[sp];
            dst[t + sp]     = sum;
            dst[t + sp + s] = make_float2(w.x * dif.x - w.y * dif.y,
                                          w.x * dif.y + w.y * dif.x);
        }
        float2* tmp = src; src = dst; dst = tmp;
    }
    __syncthreads();
}

// ---------- Pass 1 (fused Hermitian pack): rows (k2 -> x2), 4 rows/block ----------
// real(IDFT(g)) = IDFT(h), h(k)=(g(k)+conj(g(-k)))/2; z = h_{2p} + i*h_{2p+1}
// built on the fly from rows k1 / 1024-k1 of planes 2p, 2p+1.
__global__ __launch_bounds__(256) void fft_pass1(const float2* __restrict__ gP,
                                                 float2* __restrict__ T)
{
    __shared__ float2 A[1024];
    __shared__ float2 Bb[1024];
    __shared__ float2 W[512];
    __shared__ float2 R[4][512];

    int blk = blockIdx.x;
    int p   = blk >> 8;          // 4 packed planes
    int k1g = blk & 255;
    int tid = threadIdx.x;

    #pragma unroll
    for (int h = 0; h < 2; h++) {
        int j = tid + (h << 8);
        float sn, cn;
        __sincosf(6.283185307179586f * (float)j * (1.0f / 1024.0f), &sn, &cn);
        W[j] = make_float2(cn, sn);
    }

    const float2* gA = gP + ((size_t)(2 * p)     << 20);
    const float2* gB = gP + ((size_t)(2 * p + 1) << 20);

    for (int r = 0; r < 4; r++) {
        int k1  = (k1g << 2) + r;
        int nk1 = (1024 - k1) & 1023;
        const float2* rA  = gA + ((size_t)k1  << 10);
        const float2* rAn = gA + ((size_t)nk1 << 10);
        const float2* rB  = gB + ((size_t)k1  << 10);
        const float2* rBn = gB + ((size_t)nk1 << 10);
        __syncthreads();
        #pragma unroll
        for (int h = 0; h < 4; h++) {
            int k2  = tid + (h << 8);
            int nk2 = (1024 - k2) & 1023;
            float2 va  = rA[k2];
            float2 van = rAn[nk2];
            float2 vb  = rB[k2];
            float2 vbn = rBn[nk2];
            A[k2] = make_float2(0.5f * (va.x + van.x) - 0.5f * (vb.y - vbn.y),
                                0.5f * (va.y - van.y) + 0.5f * (vb.x + vbn.x));
        }
        fft1024_inv(A, Bb, W, tid);
        #pragma unroll
        for (int h = 0; h < 2; h++) {
            int xo2 = tid + (h << 8);
            R[r][xo2] = A[(xo2 + 768) & 1023];
        }
    }
    __syncthreads();

    #pragma unroll
    for (int h = 0; h < 2; h++) {
        int xo2 = tid + (h << 8);
        float2 f0 = R[0][xo2], f1 = R[1][xo2], f2 = R[2][xo2], f3 = R[3][xo2];
        float4* d4 = (float4*)(T + (((size_t)p * 512 + xo2) << 10) + (k1g << 2));
        d4[0] = make_float4(f0.x, f0.y, f1.x, f1.y);
        d4[1] = make_float4(f2.x, f2.y, f3.x, f3.y);
    }
}

// ---------- de-apodization (matches _deapod) ----------
__device__ __forceinline__ float apodf(int n) {
    float x  = ((float)n - 256.0f) * (1.0f / 1024.0f);
    float px = 3.14159265358979f * 6.0f * x;
    float t  = BETAF * BETAF - px * px;
    float st = sqrtf(fabsf(t));
    float num = (t > 0.0f) ? sinhf(st) : __sinf(st);
    return num / fmaxf(st, 1e-6f);
}

// ---------- Pass 2: columns (k1 -> x1) of packed planes, 4 cols/block;
// real -> batch 2p, imag -> batch 2p+1; coalesced float4 stores ----------
__global__ __launch_bounds__(256) void fft_pass2(const float2* __restrict__ T,
                                                 float* __restrict__ out)
{
    __shared__ float2 A[1024];
    __shared__ float2 Bb[1024];
    __shared__ float2 W[512];
    __shared__ float2 R[4][512];

    int blk = blockIdx.x;
    int p   = blk >> 7;
    int xg  = blk & 127;
    int tid = threadIdx.x;

    #pragma unroll
    for (int h = 0; h < 2; h++) {
        int j = tid + (h << 8);
        float sn, cn;
        __sincosf(6.283185307179586f * (float)j * (1.0f / 1024.0f), &sn, &cn);
        W[j] = make_float2(cn, sn);
    }

    float a2[4];
    #pragma unroll
    for (int r = 0; r < 4; r++) a2[r] = apodf((xg << 2) + r);

    for (int r = 0; r < 4; r++) {
        int xo2 = (xg << 2) + r;
        const float2* row = T + (((size_t)p * 512 + xo2) << 10);
        __syncthreads();
        #pragma unroll
        for (int h = 0; h < 4; h++) { int i = tid + (h << 8); A[i] = row[i]; }
        fft1024_inv(A, Bb, W, tid);
        #pragma unroll
        for (int h = 0; h < 2; h++) {
            int xo1 = tid + (h << 8);
            float2 v = A[(xo1 + 768) & 1023];
            R[r][xo1] = make_float2(v.x / a2[r], v.y / a2[r]);
        }
    }
    __syncthreads();

    int b0 = 2 * p;
    #pragma unroll
    for (int h = 0; h < 2; h++) {
        int xo1 = tid + (h << 8);
        float inva1 = 1.0f / apodf(xo1);
        float2 f0 = R[0][xo1], f1 = R[1][xo1], f2 = R[2][xo1], f3 = R[3][xo1];
        float4* o0 = (float4*)(out + (((size_t)b0 * 512 + xo1) << 9) + (xg << 2));
        float4* o1 = (float4*)(out + (((size_t)(b0 + 1) * 512 + xo1) << 9) + (xg << 2));
        *o0 = make_float4(f0.x * inva1, f1.x * inva1, f2.x * inva1, f3.x * inva1);
        *o1 = make_float4(f0.y * inva1, f1.y * inva1, f2.y * inva1, f3.y * inva1);
    }
}

// ---------- host launch ----------
extern "C" void kernel_launch(void* const* d_in, const int* in_sizes, int n_in,
                              void* d_out, int out_size, void* d_ws, size_t ws_size,
                              hipStream_t stream)
{
    const float* yr  = (const float*)d_in[0];
    const float* yi  = (const float*)d_in[1];
    const float* uv  = (const float*)d_in[2];
    const float* wts = (const float*)d_in[3];

    int M = in_sizes[3];

    // ws layout (96 MB, phase-aliased):
    //  [0,64)MB : gP (8 planar batch grids); read by fused pass1
    //  [64,96)MB: prep/grid scratch (cnt/list/yF4/pnt), dead after grid_tile;
    //             then T (16 MB) written by pass1, read by pass2
    float2* gP = (float2*)d_ws;
    char*   p2 = (char*)d_ws + ((size_t)64 << 20);
    float2* T  = (float2*)p2;                                    // 16 MB
    int*    cnt  = (int*)p2;                                     // 64 KB
    int*    list = (int*)(p2 + 65536);                           // 6.29 MB (+pad)
    float4* yF4  = (float4*)(p2 + 6553600);                      // 12.8 MB (M+1 pts)
    float4* pnt  = (float4*)(p2 + 19500032);                     // 12.8 MB (M+1 pts)

    hipMemsetAsync(cnt, 0, NBIN * sizeof(int), stream);
    prep_kernel<<<dim3((M + 255) / 256), dim3(256), 0, stream>>>(
        yr, yi, uv, wts, yF4, pnt, cnt, list, M);
    grid_tile<<<dim3(NBIN / 4), dim3(256), 0, stream>>>(
        (const float*)pnt, (const float4*)yF4, cnt, list, gP, M);
    fft_pass1<<<dim3(4 * 256), dim3(256), 0, stream>>>(gP, T);
    fft_pass2<<<dim3(4 * 128), dim3(256), 0, stream>>>(T, (float*)d_out);
}